// Round 1
// baseline (5452.853 us; speedup 1.0000x reference)
//
#include <hip/hip_runtime.h>

// SplineCNN forward, MI355X baseline (round 1).
// Strategy: bucket edges by 2x2 spline cell (16 buckets); per block stage the
// bucket's 4 weight matrices in LDS; 8-edge register blocking so each LDS W
// read is reused 8x; coalesced f32 atomics into L2-resident agg buffer.

constexpr int NN = 50000;       // nodes
constexpr int EE = 800000;      // edges
constexpr int CHUNK = 128;      // edges per block in edge_kernel
constexpr int ELIST_LEN = EE + 16 * CHUNK;        // padded bucket segments
constexpr int NBLK_EDGE = EE / CHUNK + 16;        // 6266 blocks covers worst case

// ---------------------------------------------------------------- dtype probe
// Reference uses int64 edge_index; harness may pass int32. If the buffer is
// int32, interpreting consecutive pairs as int64 yields values >= 2^32 with
// overwhelming probability (needs 64 consecutive high words == 0 to misfire:
// p ~ (1/50000)^64). Deterministic: same input -> same flag.
__global__ void detect_i64(const long long* __restrict__ eidx, int* __restrict__ flag) {
  long long v = eidx[threadIdx.x];
  bool ok = (v >= 0) && (v < (long long)NN);
  unsigned long long m = __ballot(ok);
  if (threadIdx.x == 0) flag[0] = (m == ~0ull) ? 1 : 0;
}

// ------------------------------------------------------------------- prep
// src/dst int32, per-edge cell id (0..15), basis weights (float4), degree
// histogram, per-cell edge counts.
__global__ void prep_edges(const void* __restrict__ eidx, const float* __restrict__ attr,
                           const int* __restrict__ flag,
                           int* __restrict__ src, int* __restrict__ dst,
                           int* __restrict__ cell, float4* __restrict__ basis,
                           float* __restrict__ deg, int* __restrict__ cnt) {
  int e = blockIdx.x * 256 + threadIdx.x;
  if (e >= EE) return;
  int s, d;
  if (flag[0]) {
    s = (int)((const long long*)eidx)[e];
    d = (int)((const long long*)eidx)[EE + e];
  } else {
    s = ((const int*)eidx)[e];
    d = ((const int*)eidx)[EE + e];
  }
  src[e] = s;
  dst[e] = d;
  atomicAdd(&deg[d], 1.0f);
  // degree-1 open B-spline, K=5: v = attr*(K-1); bot=floor(v); frac=v-bot
  float v0 = attr[2 * e] * 4.0f, v1 = attr[2 * e + 1] * 4.0f;
  float fl0 = floorf(v0), fl1 = floorf(v1);
  float fr0 = v0 - fl0, fr1 = v1 - fl1;
  int bx = min(max((int)fl0, 0), 3);
  int by = min(max((int)fl1, 0), 3);
  int c = bx + 4 * by;
  cell[e] = c;
  float4 b;
  b.x = (1.0f - fr0) * (1.0f - fr1);  // s=0: dx=0,dy=0
  b.y = fr0 * (1.0f - fr1);           // s=1: dx=1,dy=0
  b.z = (1.0f - fr0) * fr1;           // s=2: dx=0,dy=1
  b.w = fr0 * fr1;                    // s=3: dx=1,dy=1
  basis[e] = b;
  atomicAdd(&cnt[c], 1);
}

// Exclusive scan over 16 cells, segments padded to CHUNK multiples so every
// block's chunk lies entirely inside one bucket.
__global__ void scan16(const int* __restrict__ cnt, int* __restrict__ ofs) {
  int t = 0;
  for (int c = 0; c < 16; ++c) {
    ofs[c] = t;
    t += ((cnt[c] + CHUNK - 1) / CHUNK) * CHUNK;
  }
}

__global__ void scatter_edges(const int* __restrict__ cell, const int* __restrict__ ofs,
                              int* __restrict__ fill, int* __restrict__ elist) {
  int e = blockIdx.x * 256 + threadIdx.x;
  if (e >= EE) return;
  int c = cell[e];
  int pos = ofs[c] + atomicAdd(&fill[c], 1);
  elist[pos] = e;
}

// ------------------------------------------------------------------- edge msg
// Per block: one bucket cell, CHUNK=128 edges. 4 waves x 4 groups x 8 edges.
// lane = output channel o (64); per lane acc[8 edges][4 taps].
// LDS: W [4 taps][IN][64] (straight copy, b32 reads lane-coalesced,
// conflict-free) + per-wave x slab (8 rows, b128 broadcast reads).
template <int IN>
__global__ __launch_bounds__(256) void edge_kernel(
    const float* __restrict__ x, const float* __restrict__ w,
    const int* __restrict__ elist, const int* __restrict__ cellArr,
    const int* __restrict__ src, const int* __restrict__ dst,
    const float4* __restrict__ basis, float* __restrict__ agg) {
  constexpr int XP = IN / 4;
  __shared__ float Wl[4 * IN * 64];       // 32 KB (IN=32) / 64 KB (IN=64)
  __shared__ float4 xs[4][8][XP];         // per-wave private x slabs
  const int tid = threadIdx.x;
  const int base = blockIdx.x * CHUNK;
  const int e0 = elist[base];
  if (e0 < 0) return;  // empty padded chunk (uniform across block)
  const int c = cellArr[e0];
  const int bx = c & 3, by = c >> 2;
#pragma unroll
  for (int s = 0; s < 4; ++s) {
    const int k = (bx + (s & 1)) + 5 * (by + (s >> 1));
    const float4* wk = reinterpret_cast<const float4*>(w + (size_t)k * IN * 64);
    float4* wl = reinterpret_cast<float4*>(Wl + s * IN * 64);
    for (int idx = tid; idx < IN * 16; idx += 256) wl[idx] = wk[idx];
  }
  __syncthreads();
  const int wave = tid >> 6, lane = tid & 63;
  const int j = lane >> 3, p = lane & 7;
  for (int g = 0; g < 4; ++g) {
    const int ebase = base + (wave * 4 + g) * 8;
    {  // stage 8 x rows for this wave (lane (j,p) loads row j, 16B piece p)
      const int e = elist[ebase + j];
      const int row = (e >= 0) ? src[e] : 0;
      const float4* xr = reinterpret_cast<const float4*>(x + (size_t)row * IN);
      xs[wave][j][p] = xr[p];
      if constexpr (IN == 64) xs[wave][j][p + 8] = xr[p + 8];
    }
    __syncthreads();
    float acc[8][4];
#pragma unroll
    for (int jj = 0; jj < 8; ++jj)
#pragma unroll
      for (int s = 0; s < 4; ++s) acc[jj][s] = 0.0f;
#pragma unroll 4
    for (int i4 = 0; i4 < XP; ++i4) {
      float4 xv[8];
#pragma unroll
      for (int jj = 0; jj < 8; ++jj) xv[jj] = xs[wave][jj][i4];  // LDS broadcast
#pragma unroll
      for (int s = 0; s < 4; ++s) {
        const float* wp = &Wl[(s * IN + i4 * 4) * 64 + lane];
        const float w0 = wp[0], w1 = wp[64], w2 = wp[128], w3 = wp[192];
#pragma unroll
        for (int jj = 0; jj < 8; ++jj) {
          float a = acc[jj][s];
          a = fmaf(xv[jj].x, w0, a);
          a = fmaf(xv[jj].y, w1, a);
          a = fmaf(xv[jj].z, w2, a);
          a = fmaf(xv[jj].w, w3, a);
          acc[jj][s] = a;
        }
      }
    }
    // combine taps with basis weights, scatter to dst (coalesced 256B atomics)
#pragma unroll
    for (int jj = 0; jj < 8; ++jj) {
      const int ej = elist[ebase + jj];
      if (ej >= 0) {
        const float4 b = basis[ej];
        const float msg =
            acc[jj][0] * b.x + acc[jj][1] * b.y + acc[jj][2] * b.z + acc[jj][3] * b.w;
        atomicAdd(&agg[(size_t)dst[ej] * 64 + lane], msg);
      }
    }
    __syncthreads();
  }
}

// --------------------------------------------------------------- finalize
// x_out = relu(agg/deg + x_in @ root + bias); one node per wave.
template <int IN>
__global__ __launch_bounds__(256) void finalize_kernel(
    const float* __restrict__ x_in, const float* __restrict__ agg,
    const float* __restrict__ deg, const float* __restrict__ root,
    const float* __restrict__ bias, float* __restrict__ x_out) {
  __shared__ float rl[IN * 64];
  for (int idx = threadIdx.x; idx < IN * 16; idx += 256)
    reinterpret_cast<float4*>(rl)[idx] = reinterpret_cast<const float4*>(root)[idx];
  __syncthreads();
  const int wave = threadIdx.x >> 6, lane = threadIdx.x & 63;
  const int n = blockIdx.x * 4 + wave;
  if (n >= NN) return;
  const float d = fmaxf(deg[n], 1.0f);
  float r = agg[(size_t)n * 64 + lane] / d + bias[lane];
  const float* xr = x_in + (size_t)n * IN;
#pragma unroll 8
  for (int i = 0; i < IN; ++i) r = fmaf(xr[i], rl[i * 64 + lane], r);
  x_out[(size_t)n * 64 + lane] = fmaxf(r, 0.0f);
}

// ------------------------------------------------------------------- output
// out = [x0|x1|x2] @ fw + fb (no relu). fw (160x64 = 40KB) staged in LDS.
__global__ __launch_bounds__(256) void out_kernel(
    const float* __restrict__ x0, const float* __restrict__ x1,
    const float* __restrict__ x2, const float* __restrict__ fw,
    const float* __restrict__ fb, float* __restrict__ out) {
  __shared__ float fl[160 * 64];
  for (int idx = threadIdx.x; idx < 160 * 16; idx += 256)
    reinterpret_cast<float4*>(fl)[idx] = reinterpret_cast<const float4*>(fw)[idx];
  __syncthreads();
  const int wave = threadIdx.x >> 6, lane = threadIdx.x & 63;
  const int n = blockIdx.x * 4 + wave;
  if (n >= NN) return;
  float r = fb[lane];
  const float* a = x0 + (size_t)n * 32;
#pragma unroll 8
  for (int i = 0; i < 32; ++i) r = fmaf(a[i], fl[i * 64 + lane], r);
  const float* b = x1 + (size_t)n * 64;
#pragma unroll 8
  for (int i = 0; i < 64; ++i) r = fmaf(b[i], fl[(32 + i) * 64 + lane], r);
  const float* cx = x2 + (size_t)n * 64;
#pragma unroll 8
  for (int i = 0; i < 64; ++i) r = fmaf(cx[i], fl[(96 + i) * 64 + lane], r);
  out[(size_t)n * 64 + lane] = r;
}

extern "C" void kernel_launch(void* const* d_in, const int* in_sizes, int n_in,
                              void* d_out, int out_size, void* d_ws, size_t ws_size,
                              hipStream_t stream) {
  const float* x0 = (const float*)d_in[0];
  const void* eidx = d_in[1];
  const float* attr = (const float*)d_in[2];
  const float* w0 = (const float*)d_in[3];
  const float* root0 = (const float*)d_in[4];
  const float* b0 = (const float*)d_in[5];
  const float* w1 = (const float*)d_in[6];
  const float* root1 = (const float*)d_in[7];
  const float* b1 = (const float*)d_in[8];
  const float* fw = (const float*)d_in[9];
  const float* fb = (const float*)d_in[10];
  float* out = (float*)d_out;
  (void)in_sizes; (void)n_in; (void)out_size; (void)ws_size;

  char* wsb = (char*)d_ws;
  size_t off = 0;
  auto alloc = [&](size_t bytes) -> void* {
    void* p = wsb + off;
    off += (bytes + 255) & ~(size_t)255;
    return p;
  };
  int* flag = (int*)alloc(256);
  int* src = (int*)alloc(sizeof(int) * EE);
  int* dst = (int*)alloc(sizeof(int) * EE);
  int* cell = (int*)alloc(sizeof(int) * EE);
  float4* basis = (float4*)alloc(sizeof(float4) * EE);
  int* elist = (int*)alloc(sizeof(int) * ELIST_LEN);
  float* deg = (float*)alloc(sizeof(float) * NN);
  int* cnt = (int*)alloc(256);
  int* ofs = (int*)alloc(256);
  int* fill = (int*)alloc(256);
  float* agg = (float*)alloc(sizeof(float) * NN * 64);
  float* x1 = (float*)alloc(sizeof(float) * NN * 64);
  float* x2 = (float*)alloc(sizeof(float) * NN * 64);
  // total ~62 MB of d_ws

  hipMemsetAsync(deg, 0, sizeof(float) * NN, stream);
  hipMemsetAsync(cnt, 0, 256, stream);
  hipMemsetAsync(fill, 0, 256, stream);
  hipMemsetAsync(elist, 0xFF, sizeof(int) * ELIST_LEN, stream);  // -1 sentinels

  detect_i64<<<1, 64, 0, stream>>>((const long long*)eidx, flag);
  prep_edges<<<(EE + 255) / 256, 256, 0, stream>>>(eidx, attr, flag, src, dst, cell,
                                                   basis, deg, cnt);
  scan16<<<1, 1, 0, stream>>>(cnt, ofs);
  scatter_edges<<<(EE + 255) / 256, 256, 0, stream>>>(cell, ofs, fill, elist);

  // layer 0: in=32
  hipMemsetAsync(agg, 0, sizeof(float) * NN * 64, stream);
  edge_kernel<32><<<NBLK_EDGE, 256, 0, stream>>>(x0, w0, elist, cell, src, dst, basis, agg);
  finalize_kernel<32><<<(NN + 3) / 4, 256, 0, stream>>>(x0, agg, deg, root0, b0, x1);

  // layer 1: in=64
  hipMemsetAsync(agg, 0, sizeof(float) * NN * 64, stream);
  edge_kernel<64><<<NBLK_EDGE, 256, 0, stream>>>(x1, w1, elist, cell, src, dst, basis, agg);
  finalize_kernel<64><<<(NN + 3) / 4, 256, 0, stream>>>(x1, agg, deg, root1, b1, x2);

  out_kernel<<<(NN + 3) / 4, 256, 0, stream>>>(x0, x1, x2, fw, fb, out);
}

// Round 2
// 1177.485 us; speedup vs baseline: 4.6309x; 4.6309x over previous
//
#include <hip/hip_runtime.h>

// SplineCNN forward, MI355X round 2.
// R1 -> R2: the 16-counter global atomics in prep/scatter were ~4.5ms of pure
// contention (rocprof: scatter 33ms under replay, prep 2164us, VALUBusy~0).
// Replaced with a deterministic, atomic-free counting sort:
//   per-block ballot histograms -> 1-block shfl scan -> deterministic scatter.

constexpr int NN = 50000;       // nodes
constexpr int EE = 800000;      // edges
constexpr int CHUNK = 128;      // edges per block in edge_kernel
constexpr int EB = EE / 256;    // 3125 prep/scatter blocks (EE % 256 == 0)
static_assert(EE % 256 == 0, "prep grid assumes exact divisibility");
constexpr int ELIST_LEN = EE + 16 * CHUNK;        // padded bucket segments
constexpr int NBLK_EDGE = EE / CHUNK + 16;        // 6266 blocks covers worst case

// ---------------------------------------------------------------- dtype probe
// Reference uses int64 edge_index; harness may pass int32. If the buffer is
// int32, interpreting consecutive pairs as int64 yields values >= 2^32 with
// overwhelming probability. Deterministic: same input -> same flag.
__global__ void detect_i64(const long long* __restrict__ eidx, int* __restrict__ flag) {
  long long v = eidx[threadIdx.x];
  bool ok = (v >= 0) && (v < (long long)NN);
  unsigned long long m = __ballot(ok);
  if (threadIdx.x == 0) flag[0] = (m == ~0ull) ? 1 : 0;
}

// ------------------------------------------------------------------- prep
// src/dst int32, per-edge cell id (0..15), basis weights (float4), degree
// histogram (atomics over 50k addrs - uncontended), per-BLOCK cell histogram
// via ballots (no global atomics).
__global__ __launch_bounds__(256) void prep_edges(
    const void* __restrict__ eidx, const float* __restrict__ attr,
    const int* __restrict__ flag,
    int* __restrict__ src, int* __restrict__ dst,
    int* __restrict__ cell, float4* __restrict__ basis,
    float* __restrict__ deg, int* __restrict__ bh) {
  __shared__ int wc[4][16];
  const int tid = threadIdx.x;
  const int e = blockIdx.x * 256 + tid;
  int s, d;
  if (flag[0]) {
    s = (int)((const long long*)eidx)[e];
    d = (int)((const long long*)eidx)[EE + e];
  } else {
    s = ((const int*)eidx)[e];
    d = ((const int*)eidx)[EE + e];
  }
  src[e] = s;
  dst[e] = d;
  atomicAdd(&deg[d], 1.0f);
  // degree-1 open B-spline, K=5: v = attr*(K-1); bot=floor(v); frac=v-bot
  float v0 = attr[2 * e] * 4.0f, v1 = attr[2 * e + 1] * 4.0f;
  float fl0 = floorf(v0), fl1 = floorf(v1);
  float fr0 = v0 - fl0, fr1 = v1 - fl1;
  int bx = min(max((int)fl0, 0), 3);
  int by = min(max((int)fl1, 0), 3);
  const int c = bx + 4 * by;
  cell[e] = c;
  float4 b;
  b.x = (1.0f - fr0) * (1.0f - fr1);  // s=0: dx=0,dy=0
  b.y = fr0 * (1.0f - fr1);           // s=1: dx=1,dy=0
  b.z = (1.0f - fr0) * fr1;           // s=2: dx=0,dy=1
  b.w = fr0 * fr1;                    // s=3: dx=1,dy=1
  basis[e] = b;
  // per-block histogram: 16 ballots per wave, zero atomics
  const int wave = tid >> 6, lane = tid & 63;
#pragma unroll
  for (int k = 0; k < 16; ++k) {
    unsigned long long m = __ballot(c == k);
    if (lane == k) wc[wave][k] = __popcll(m);
  }
  __syncthreads();
  if (tid < 16)
    bh[blockIdx.x * 16 + tid] = wc[0][tid] + wc[1][tid] + wc[2][tid] + wc[3][tid];
}

// One block, 16 waves. Wave w owns cell w: total count, padded cell offset,
// then an exclusive prefix over the 3125 block histograms -> per-block base.
__global__ __launch_bounds__(1024) void scan_offsets(
    const int* __restrict__ bh, int* __restrict__ blkbase) {
  __shared__ int tot[16];
  __shared__ int ofs_s[16];
  const int wave = threadIdx.x >> 6, lane = threadIdx.x & 63;
  {  // totals per cell
    int sum = 0;
    for (int b = lane; b < EB; b += 64) sum += bh[b * 16 + wave];
#pragma unroll
    for (int off = 32; off > 0; off >>= 1) sum += __shfl_down(sum, off);
    if (lane == 0) tot[wave] = sum;
  }
  __syncthreads();
  if (threadIdx.x == 0) {
    int t = 0;
    for (int c = 0; c < 16; ++c) {
      ofs_s[c] = t;
      t += ((tot[c] + CHUNK - 1) / CHUNK) * CHUNK;
    }
  }
  __syncthreads();
  int running = ofs_s[wave];
  for (int b0 = 0; b0 < EB; b0 += 64) {
    const int b = b0 + lane;
    const int v = (b < EB) ? bh[b * 16 + wave] : 0;
    int inc = v;
#pragma unroll
    for (int off = 1; off < 64; off <<= 1) {
      int n = __shfl_up(inc, off);
      if (lane >= off) inc += n;
    }
    if (b < EB) blkbase[b * 16 + wave] = running + (inc - v);
    running += __shfl(inc, 63);
  }
}

// Deterministic scatter: ballot rank within wave + LDS scan across the 4 waves.
__global__ __launch_bounds__(256) void scatter_edges(
    const int* __restrict__ cell, const int* __restrict__ blkbase,
    int* __restrict__ elist) {
  __shared__ int wc[4][16];
  __shared__ int bs[4][16];
  const int tid = threadIdx.x;
  const int e = blockIdx.x * 256 + tid;
  const int c = cell[e];
  const int wave = tid >> 6, lane = tid & 63;
  int rank = 0;
#pragma unroll
  for (int k = 0; k < 16; ++k) {
    unsigned long long m = __ballot(c == k);
    if (k == c) rank = __popcll(m & ((1ull << lane) - 1ull));
    if (lane == k) wc[wave][k] = __popcll(m);
  }
  __syncthreads();
  if (tid < 16) {
    int running = blkbase[blockIdx.x * 16 + tid];
#pragma unroll
    for (int w = 0; w < 4; ++w) { bs[w][tid] = running; running += wc[w][tid]; }
  }
  __syncthreads();
  elist[bs[wave][c] + rank] = e;
}

// ------------------------------------------------------------------- edge msg
// Per block: one bucket cell, CHUNK=128 edges. 4 waves x 4 groups x 8 edges.
// lane = output channel o (64); per lane acc[8 edges][4 taps].
// LDS: W [4 taps][IN][64] (straight copy, b32 reads lane-coalesced,
// conflict-free) + per-wave x slab (8 rows, b128 broadcast reads).
template <int IN>
__global__ __launch_bounds__(256) void edge_kernel(
    const float* __restrict__ x, const float* __restrict__ w,
    const int* __restrict__ elist, const int* __restrict__ cellArr,
    const int* __restrict__ src, const int* __restrict__ dst,
    const float4* __restrict__ basis, float* __restrict__ agg) {
  constexpr int XP = IN / 4;
  __shared__ float Wl[4 * IN * 64];       // 32 KB (IN=32) / 64 KB (IN=64)
  __shared__ float4 xs[4][8][XP];         // per-wave private x slabs
  const int tid = threadIdx.x;
  const int base = blockIdx.x * CHUNK;
  const int e0 = elist[base];
  if (e0 < 0) return;  // empty padded chunk (uniform across block)
  const int c = cellArr[e0];
  const int bx = c & 3, by = c >> 2;
#pragma unroll
  for (int s = 0; s < 4; ++s) {
    const int k = (bx + (s & 1)) + 5 * (by + (s >> 1));
    const float4* wk = reinterpret_cast<const float4*>(w + (size_t)k * IN * 64);
    float4* wl = reinterpret_cast<float4*>(Wl + s * IN * 64);
    for (int idx = tid; idx < IN * 16; idx += 256) wl[idx] = wk[idx];
  }
  __syncthreads();
  const int wave = tid >> 6, lane = tid & 63;
  const int j = lane >> 3, p = lane & 7;
  for (int g = 0; g < 4; ++g) {
    const int ebase = base + (wave * 4 + g) * 8;
    {  // stage 8 x rows for this wave (lane (j,p) loads row j, 16B piece p)
      const int e = elist[ebase + j];
      const int row = (e >= 0) ? src[e] : 0;
      const float4* xr = reinterpret_cast<const float4*>(x + (size_t)row * IN);
      xs[wave][j][p] = xr[p];
      if constexpr (IN == 64) xs[wave][j][p + 8] = xr[p + 8];
    }
    __syncthreads();
    float acc[8][4];
#pragma unroll
    for (int jj = 0; jj < 8; ++jj)
#pragma unroll
      for (int s = 0; s < 4; ++s) acc[jj][s] = 0.0f;
#pragma unroll 4
    for (int i4 = 0; i4 < XP; ++i4) {
      float4 xv[8];
#pragma unroll
      for (int jj = 0; jj < 8; ++jj) xv[jj] = xs[wave][jj][i4];  // LDS broadcast
#pragma unroll
      for (int s = 0; s < 4; ++s) {
        const float* wp = &Wl[(s * IN + i4 * 4) * 64 + lane];
        const float w0 = wp[0], w1 = wp[64], w2 = wp[128], w3 = wp[192];
#pragma unroll
        for (int jj = 0; jj < 8; ++jj) {
          float a = acc[jj][s];
          a = fmaf(xv[jj].x, w0, a);
          a = fmaf(xv[jj].y, w1, a);
          a = fmaf(xv[jj].z, w2, a);
          a = fmaf(xv[jj].w, w3, a);
          acc[jj][s] = a;
        }
      }
    }
    // combine taps with basis weights, scatter to dst (coalesced 256B atomics)
#pragma unroll
    for (int jj = 0; jj < 8; ++jj) {
      const int ej = elist[ebase + jj];
      if (ej >= 0) {
        const float4 b = basis[ej];
        const float msg =
            acc[jj][0] * b.x + acc[jj][1] * b.y + acc[jj][2] * b.z + acc[jj][3] * b.w;
        atomicAdd(&agg[(size_t)dst[ej] * 64 + lane], msg);
      }
    }
    __syncthreads();
  }
}

// --------------------------------------------------------------- finalize
// x_out = relu(agg/deg + x_in @ root + bias); one node per wave.
template <int IN>
__global__ __launch_bounds__(256) void finalize_kernel(
    const float* __restrict__ x_in, const float* __restrict__ agg,
    const float* __restrict__ deg, const float* __restrict__ root,
    const float* __restrict__ bias, float* __restrict__ x_out) {
  __shared__ float rl[IN * 64];
  for (int idx = threadIdx.x; idx < IN * 16; idx += 256)
    reinterpret_cast<float4*>(rl)[idx] = reinterpret_cast<const float4*>(root)[idx];
  __syncthreads();
  const int wave = threadIdx.x >> 6, lane = threadIdx.x & 63;
  const int n = blockIdx.x * 4 + wave;
  if (n >= NN) return;
  const float d = fmaxf(deg[n], 1.0f);
  float r = agg[(size_t)n * 64 + lane] / d + bias[lane];
  const float* xr = x_in + (size_t)n * IN;
#pragma unroll 8
  for (int i = 0; i < IN; ++i) r = fmaf(xr[i], rl[i * 64 + lane], r);
  x_out[(size_t)n * 64 + lane] = fmaxf(r, 0.0f);
}

// ------------------------------------------------------------------- output
// out = [x0|x1|x2] @ fw + fb (no relu). fw (160x64 = 40KB) staged in LDS.
__global__ __launch_bounds__(256) void out_kernel(
    const float* __restrict__ x0, const float* __restrict__ x1,
    const float* __restrict__ x2, const float* __restrict__ fw,
    const float* __restrict__ fb, float* __restrict__ out) {
  __shared__ float fl[160 * 64];
  for (int idx = threadIdx.x; idx < 160 * 16; idx += 256)
    reinterpret_cast<float4*>(fl)[idx] = reinterpret_cast<const float4*>(fw)[idx];
  __syncthreads();
  const int wave = threadIdx.x >> 6, lane = threadIdx.x & 63;
  const int n = blockIdx.x * 4 + wave;
  if (n >= NN) return;
  float r = fb[lane];
  const float* a = x0 + (size_t)n * 32;
#pragma unroll 8
  for (int i = 0; i < 32; ++i) r = fmaf(a[i], fl[i * 64 + lane], r);
  const float* b = x1 + (size_t)n * 64;
#pragma unroll 8
  for (int i = 0; i < 64; ++i) r = fmaf(b[i], fl[(32 + i) * 64 + lane], r);
  const float* cx = x2 + (size_t)n * 64;
#pragma unroll 8
  for (int i = 0; i < 64; ++i) r = fmaf(cx[i], fl[(96 + i) * 64 + lane], r);
  out[(size_t)n * 64 + lane] = r;
}

extern "C" void kernel_launch(void* const* d_in, const int* in_sizes, int n_in,
                              void* d_out, int out_size, void* d_ws, size_t ws_size,
                              hipStream_t stream) {
  const float* x0 = (const float*)d_in[0];
  const void* eidx = d_in[1];
  const float* attr = (const float*)d_in[2];
  const float* w0 = (const float*)d_in[3];
  const float* root0 = (const float*)d_in[4];
  const float* b0 = (const float*)d_in[5];
  const float* w1 = (const float*)d_in[6];
  const float* root1 = (const float*)d_in[7];
  const float* b1 = (const float*)d_in[8];
  const float* fw = (const float*)d_in[9];
  const float* fb = (const float*)d_in[10];
  float* out = (float*)d_out;
  (void)in_sizes; (void)n_in; (void)out_size; (void)ws_size;

  char* wsb = (char*)d_ws;
  size_t off = 0;
  auto alloc = [&](size_t bytes) -> void* {
    void* p = wsb + off;
    off += (bytes + 255) & ~(size_t)255;
    return p;
  };
  int* flag = (int*)alloc(256);
  int* src = (int*)alloc(sizeof(int) * EE);
  int* dst = (int*)alloc(sizeof(int) * EE);
  int* cell = (int*)alloc(sizeof(int) * EE);
  float4* basis = (float4*)alloc(sizeof(float4) * EE);
  int* elist = (int*)alloc(sizeof(int) * ELIST_LEN);
  float* deg = (float*)alloc(sizeof(float) * NN);
  int* bh = (int*)alloc(sizeof(int) * EB * 16);       // per-block cell hist
  int* blkbase = (int*)alloc(sizeof(int) * EB * 16);  // per-block scatter base
  float* agg = (float*)alloc(sizeof(float) * NN * 64);
  float* x1 = (float*)alloc(sizeof(float) * NN * 64);
  float* x2 = (float*)alloc(sizeof(float) * NN * 64);
  // total ~62 MB of d_ws

  hipMemsetAsync(deg, 0, sizeof(float) * NN, stream);
  hipMemsetAsync(elist, 0xFF, sizeof(int) * ELIST_LEN, stream);  // -1 sentinels

  detect_i64<<<1, 64, 0, stream>>>((const long long*)eidx, flag);
  prep_edges<<<EB, 256, 0, stream>>>(eidx, attr, flag, src, dst, cell, basis, deg, bh);
  scan_offsets<<<1, 1024, 0, stream>>>(bh, blkbase);
  scatter_edges<<<EB, 256, 0, stream>>>(cell, blkbase, elist);

  // layer 0: in=32
  hipMemsetAsync(agg, 0, sizeof(float) * NN * 64, stream);
  edge_kernel<32><<<NBLK_EDGE, 256, 0, stream>>>(x0, w0, elist, cell, src, dst, basis, agg);
  finalize_kernel<32><<<(NN + 3) / 4, 256, 0, stream>>>(x0, agg, deg, root0, b0, x1);

  // layer 1: in=64
  hipMemsetAsync(agg, 0, sizeof(float) * NN * 64, stream);
  edge_kernel<64><<<NBLK_EDGE, 256, 0, stream>>>(x1, w1, elist, cell, src, dst, basis, agg);
  finalize_kernel<64><<<(NN + 3) / 4, 256, 0, stream>>>(x1, agg, deg, root1, b1, x2);

  out_kernel<<<(NN + 3) / 4, 256, 0, stream>>>(x0, x1, x2, fw, fb, out);
}

// Round 3
// 688.300 us; speedup vs baseline: 7.9222x; 1.7107x over previous
//
#include <hip/hip_runtime.h>
#include <hip/hip_bf16.h>

// SplineCNN forward, MI355X round 3.
// R2 -> R3: edge transform moved to bf16 MFMA (16x16x32). Per block (one
// spline cell, 512 edges): stage Wcat^T = [W[k0];..;W[k3]]^T as bf16 in LDS
// (xor-swizzled), hoist B-fragments to registers (shared by all edges), build
// A-fragments in registers as basis[s] * x[src] with cvt_pk bf16, fp32 acc.
// 1-tile software pipeline on the gather chain. No LDS in the main loop.

typedef __attribute__((ext_vector_type(8))) short short8v;
typedef __attribute__((ext_vector_type(4))) float f32x4;

constexpr int NN = 50000;       // nodes
constexpr int EE = 800000;      // edges
constexpr int CHUNK = 512;      // edges per block in edge_mfma
constexpr int EB = EE / 256;    // 3125 prep/scatter blocks
static_assert(EE % 256 == 0, "prep grid assumes exact divisibility");
constexpr int ELIST_LEN = EE + 16 * CHUNK;
constexpr int NBLK_EDGE = EE / CHUNK + 16;   // 1578: covers all padded segments

__device__ __forceinline__ short f2bf(float f) {
  return __builtin_bit_cast(short, __float2bfloat16(f));  // RNE, cvt_pk-able
}

// ---------------------------------------------------------------- dtype probe
__global__ void detect_i64(const long long* __restrict__ eidx, int* __restrict__ flag) {
  long long v = eidx[threadIdx.x];
  bool ok = (v >= 0) && (v < (long long)NN);
  unsigned long long m = __ballot(ok);
  if (threadIdx.x == 0) flag[0] = (m == ~0ull) ? 1 : 0;
}

// ------------------------------------------------------------------- prep
__global__ __launch_bounds__(256) void prep_edges(
    const void* __restrict__ eidx, const float* __restrict__ attr,
    const int* __restrict__ flag,
    int* __restrict__ src, int* __restrict__ dst,
    int* __restrict__ cell, float4* __restrict__ basis,
    float* __restrict__ deg, int* __restrict__ bh) {
  __shared__ int wc[4][16];
  const int tid = threadIdx.x;
  const int e = blockIdx.x * 256 + tid;
  int s, d;
  if (flag[0]) {
    s = (int)((const long long*)eidx)[e];
    d = (int)((const long long*)eidx)[EE + e];
  } else {
    s = ((const int*)eidx)[e];
    d = ((const int*)eidx)[EE + e];
  }
  src[e] = s;
  dst[e] = d;
  atomicAdd(&deg[d], 1.0f);
  float v0 = attr[2 * e] * 4.0f, v1 = attr[2 * e + 1] * 4.0f;
  float fl0 = floorf(v0), fl1 = floorf(v1);
  float fr0 = v0 - fl0, fr1 = v1 - fl1;
  int bx = min(max((int)fl0, 0), 3);
  int by = min(max((int)fl1, 0), 3);
  const int c = bx + 4 * by;
  cell[e] = c;
  float4 b;
  b.x = (1.0f - fr0) * (1.0f - fr1);
  b.y = fr0 * (1.0f - fr1);
  b.z = (1.0f - fr0) * fr1;
  b.w = fr0 * fr1;
  basis[e] = b;
  const int wave = tid >> 6, lane = tid & 63;
#pragma unroll
  for (int k = 0; k < 16; ++k) {
    unsigned long long mm = __ballot(c == k);
    if (lane == k) wc[wave][k] = __popcll(mm);
  }
  __syncthreads();
  if (tid < 16)
    bh[blockIdx.x * 16 + tid] = wc[0][tid] + wc[1][tid] + wc[2][tid] + wc[3][tid];
}

// One block, 16 waves: per-cell totals, padded offsets, per-block bases.
__global__ __launch_bounds__(1024) void scan_offsets(
    const int* __restrict__ bh, int* __restrict__ blkbase) {
  __shared__ int tot[16];
  __shared__ int ofs_s[16];
  const int wave = threadIdx.x >> 6, lane = threadIdx.x & 63;
  {
    int sum = 0;
    for (int b = lane; b < EB; b += 64) sum += bh[b * 16 + wave];
#pragma unroll
    for (int off = 32; off > 0; off >>= 1) sum += __shfl_down(sum, off);
    if (lane == 0) tot[wave] = sum;
  }
  __syncthreads();
  if (threadIdx.x == 0) {
    int t = 0;
    for (int c = 0; c < 16; ++c) {
      ofs_s[c] = t;
      t += ((tot[c] + CHUNK - 1) / CHUNK) * CHUNK;
    }
  }
  __syncthreads();
  int running = ofs_s[wave];
  for (int b0 = 0; b0 < EB; b0 += 64) {
    const int b = b0 + lane;
    const int v = (b < EB) ? bh[b * 16 + wave] : 0;
    int inc = v;
#pragma unroll
    for (int off = 1; off < 64; off <<= 1) {
      int n = __shfl_up(inc, off);
      if (lane >= off) inc += n;
    }
    if (b < EB) blkbase[b * 16 + wave] = running + (inc - v);
    running += __shfl(inc, 63);
  }
}

__global__ __launch_bounds__(256) void scatter_edges(
    const int* __restrict__ cell, const int* __restrict__ blkbase,
    int* __restrict__ elist) {
  __shared__ int wc[4][16];
  __shared__ int bs[4][16];
  const int tid = threadIdx.x;
  const int e = blockIdx.x * 256 + tid;
  const int c = cell[e];
  const int wave = tid >> 6, lane = tid & 63;
  int rank = 0;
#pragma unroll
  for (int k = 0; k < 16; ++k) {
    unsigned long long mm = __ballot(c == k);
    if (k == c) rank = __popcll(mm & ((1ull << lane) - 1ull));
    if (lane == k) wc[wave][k] = __popcll(mm);
  }
  __syncthreads();
  if (tid < 16) {
    int running = blkbase[blockIdx.x * 16 + tid];
#pragma unroll
    for (int w = 0; w < 4; ++w) { bs[w][tid] = running; running += wc[w][tid]; }
  }
  __syncthreads();
  elist[bs[wave][c] + rank] = e;
}

// ------------------------------------------------------------------- edge msg
// MFMA version. M-tile = 16 edges, N = 64 out (4 N-tiles), K = 4*IN.
// A-frag (lane l): row m=l&15, k = 32*ks + (l>>4)*8 + j  (k-contiguous 8).
// B-frag (lane l): col n=nt*16+(l&15), same k mapping -> read Wt[n][k] b128.
// C/D: col = lane&15, row = (lane>>4)*4 + reg (verified mapping).
template <int IN>
__global__ __launch_bounds__(256) void edge_mfma(
    const float* __restrict__ x, const float* __restrict__ w,
    const int* __restrict__ elist, const int* __restrict__ cellArr,
    const int* __restrict__ src, const int* __restrict__ dst,
    const float4* __restrict__ basis, float* __restrict__ agg) {
  constexpr int K = 4 * IN;
  constexpr int KSTEPS = K / 32;
  constexpr int RS = K * 2;            // LDS row stride (bytes)
  constexpr int OPR = K / 8;           // 16B octets per row
  __shared__ short8v Wt[64 * OPR];     // [64 n][K k] bf16, xor-swizzled
  const int tid = threadIdx.x;
  const int base = blockIdx.x * CHUNK;
  const int e0 = elist[base];
  if (e0 < 0) return;                  // fully-padded chunk (block-uniform)
  {
    const int c = cellArr[e0];
    const int bx = c & 3, by = c >> 2;
    for (int o = tid; o < 64 * OPR; o += 256) {
      const int n = o / OPR;
      const int k0 = (o - n * OPR) * 8;
      const int s = k0 / IN;
      const int i0 = k0 - s * IN;
      const int kk = (bx + (s & 1)) + 5 * (by + (s >> 1));
      const float* wp = w + ((size_t)kk * IN + i0) * 64 + n;
      short8v v;
#pragma unroll
      for (int j = 0; j < 8; ++j) v[j] = f2bf(wp[(size_t)j * 64]);
      const int byte = n * RS + ((k0 * 2) ^ ((n & 15) << 4));
      Wt[byte >> 4] = v;
    }
  }
  __syncthreads();
  const int lane = tid & 63;
  const int wave = tid >> 6;
  const int g = lane >> 4, m = lane & 15;
  // B fragments -> registers (shared across all edges of the block)
  short8v bfr[4][KSTEPS];
#pragma unroll
  for (int nt = 0; nt < 4; ++nt) {
    const int n = nt * 16 + m;
#pragma unroll
    for (int ks = 0; ks < KSTEPS; ++ks) {
      const int byte = n * RS + (((ks * 64) + g * 16) ^ ((n & 15) << 4));
      bfr[nt][ks] = Wt[byte >> 4];
    }
  }
  constexpr int TILES = CHUNK / 64;    // M-tiles per wave
  const int wbase = base + wave * (CHUNK / 4);
  // ---- pipeline prologue: tile 0 ----
  int e_c = elist[wbase + m];
  bool v_c = e_c >= 0;
  int row_c = v_c ? src[e_c] : 0;
  int dv_c = v_c ? dst[e_c] : 0;
  float4 bas_c = make_float4(0.f, 0.f, 0.f, 0.f);
  if (v_c) bas_c = basis[e_c];
  const float* xr0 = x + (size_t)row_c * IN;
  float4 xa_c = *reinterpret_cast<const float4*>(xr0 + g * 8);
  float4 xb_c = *reinterpret_cast<const float4*>(xr0 + g * 8 + 4);
  float4 xc_c = make_float4(0.f, 0.f, 0.f, 0.f);
  float4 xd_c = make_float4(0.f, 0.f, 0.f, 0.f);
  if constexpr (IN == 64) {
    xc_c = *reinterpret_cast<const float4*>(xr0 + 32 + g * 8);
    xd_c = *reinterpret_cast<const float4*>(xr0 + 36 + g * 8);
  }
  for (int t = 0; t < TILES; ++t) {
    // first link of next tile's gather chain, issued before compute
    const int e_nx = (t + 1 < TILES) ? elist[wbase + (t + 1) * 16 + m] : -1;
    float xv0[8] = {xa_c.x, xa_c.y, xa_c.z, xa_c.w, xb_c.x, xb_c.y, xb_c.z, xb_c.w};
    float xv1[8] = {xc_c.x, xc_c.y, xc_c.z, xc_c.w, xd_c.x, xd_c.y, xd_c.z, xd_c.w};
    f32x4 acc[4];
#pragma unroll
    for (int nt = 0; nt < 4; ++nt) acc[nt] = (f32x4){0.f, 0.f, 0.f, 0.f};
#pragma unroll
    for (int ks = 0; ks < KSTEPS; ++ks) {
      const int s = (IN == 64) ? (ks >> 1) : ks;
      const float bs = (s == 0) ? bas_c.x : (s == 1) ? bas_c.y
                     : (s == 2) ? bas_c.z : bas_c.w;
      short8v a;
#pragma unroll
      for (int j = 0; j < 8; ++j) {
        const float xf = (IN == 32 || (ks & 1) == 0) ? xv0[j] : xv1[j];
        a[j] = f2bf(bs * xf);
      }
#pragma unroll
      for (int nt = 0; nt < 4; ++nt)
        acc[nt] = __builtin_amdgcn_mfma_f32_16x16x32_bf16(a, bfr[nt][ks], acc[nt], 0, 0, 0);
    }
    // next tile's dependent loads (e_nx has landed during the MFMAs)
    const bool v_n = e_nx >= 0;
    const int row_n = v_n ? src[e_nx] : 0;
    const int dv_n = v_n ? dst[e_nx] : 0;
    float4 bas_n = make_float4(0.f, 0.f, 0.f, 0.f);
    if (v_n) bas_n = basis[e_nx];
    const float* xrn = x + (size_t)row_n * IN;
    float4 xa_n = *reinterpret_cast<const float4*>(xrn + g * 8);
    float4 xb_n = *reinterpret_cast<const float4*>(xrn + g * 8 + 4);
    float4 xc_n = make_float4(0.f, 0.f, 0.f, 0.f);
    float4 xd_n = make_float4(0.f, 0.f, 0.f, 0.f);
    if constexpr (IN == 64) {
      xc_n = *reinterpret_cast<const float4*>(xrn + 32 + g * 8);
      xd_n = *reinterpret_cast<const float4*>(xrn + 36 + g * 8);
    }
    // epilogue: D row = edge (lane>>4)*4+r, D col = nt*16 + (lane&15)
#pragma unroll
    for (int r = 0; r < 4; ++r) {
      const int m2 = g * 4 + r;
      const int er = __shfl(e_c, m2);
      const int dr = __shfl(dv_c, m2);
      if (er >= 0) {
        float* ap = agg + (size_t)dr * 64 + m;
#pragma unroll
        for (int nt = 0; nt < 4; ++nt) atomicAdd(ap + nt * 16, acc[nt][r]);
      }
    }
    e_c = e_nx; v_c = v_n; dv_c = dv_n; bas_c = bas_n;
    xa_c = xa_n; xb_c = xb_n; xc_c = xc_n; xd_c = xd_n;
  }
}

// --------------------------------------------------------------- finalize
template <int IN>
__global__ __launch_bounds__(256) void finalize_kernel(
    const float* __restrict__ x_in, const float* __restrict__ agg,
    const float* __restrict__ deg, const float* __restrict__ root,
    const float* __restrict__ bias, float* __restrict__ x_out) {
  __shared__ float rl[IN * 64];
  for (int idx = threadIdx.x; idx < IN * 16; idx += 256)
    reinterpret_cast<float4*>(rl)[idx] = reinterpret_cast<const float4*>(root)[idx];
  __syncthreads();
  const int wave = threadIdx.x >> 6, lane = threadIdx.x & 63;
  const int n = blockIdx.x * 4 + wave;
  if (n >= NN) return;
  const float d = fmaxf(deg[n], 1.0f);
  float r = agg[(size_t)n * 64 + lane] / d + bias[lane];
  const float* xr = x_in + (size_t)n * IN;
#pragma unroll 8
  for (int i = 0; i < IN; ++i) r = fmaf(xr[i], rl[i * 64 + lane], r);
  x_out[(size_t)n * 64 + lane] = fmaxf(r, 0.0f);
}

// ------------------------------------------------------------------- output
__global__ __launch_bounds__(256) void out_kernel(
    const float* __restrict__ x0, const float* __restrict__ x1,
    const float* __restrict__ x2, const float* __restrict__ fw,
    const float* __restrict__ fb, float* __restrict__ out) {
  __shared__ float fl[160 * 64];
  for (int idx = threadIdx.x; idx < 160 * 16; idx += 256)
    reinterpret_cast<float4*>(fl)[idx] = reinterpret_cast<const float4*>(fw)[idx];
  __syncthreads();
  const int wave = threadIdx.x >> 6, lane = threadIdx.x & 63;
  const int n = blockIdx.x * 4 + wave;
  if (n >= NN) return;
  float r = fb[lane];
  const float* a = x0 + (size_t)n * 32;
#pragma unroll 8
  for (int i = 0; i < 32; ++i) r = fmaf(a[i], fl[i * 64 + lane], r);
  const float* b = x1 + (size_t)n * 64;
#pragma unroll 8
  for (int i = 0; i < 64; ++i) r = fmaf(b[i], fl[(32 + i) * 64 + lane], r);
  const float* cx = x2 + (size_t)n * 64;
#pragma unroll 8
  for (int i = 0; i < 64; ++i) r = fmaf(cx[i], fl[(96 + i) * 64 + lane], r);
  out[(size_t)n * 64 + lane] = r;
}

extern "C" void kernel_launch(void* const* d_in, const int* in_sizes, int n_in,
                              void* d_out, int out_size, void* d_ws, size_t ws_size,
                              hipStream_t stream) {
  const float* x0 = (const float*)d_in[0];
  const void* eidx = d_in[1];
  const float* attr = (const float*)d_in[2];
  const float* w0 = (const float*)d_in[3];
  const float* root0 = (const float*)d_in[4];
  const float* b0 = (const float*)d_in[5];
  const float* w1 = (const float*)d_in[6];
  const float* root1 = (const float*)d_in[7];
  const float* b1 = (const float*)d_in[8];
  const float* fw = (const float*)d_in[9];
  const float* fb = (const float*)d_in[10];
  float* out = (float*)d_out;
  (void)in_sizes; (void)n_in; (void)out_size; (void)ws_size;

  char* wsb = (char*)d_ws;
  size_t off = 0;
  auto alloc = [&](size_t bytes) -> void* {
    void* p = wsb + off;
    off += (bytes + 255) & ~(size_t)255;
    return p;
  };
  int* flag = (int*)alloc(256);
  int* src = (int*)alloc(sizeof(int) * EE);
  int* dst = (int*)alloc(sizeof(int) * EE);
  int* cell = (int*)alloc(sizeof(int) * EE);
  float4* basis = (float4*)alloc(sizeof(float4) * EE);
  int* elist = (int*)alloc(sizeof(int) * ELIST_LEN);
  float* deg = (float*)alloc(sizeof(float) * NN);
  int* bh = (int*)alloc(sizeof(int) * EB * 16);
  int* blkbase = (int*)alloc(sizeof(int) * EB * 16);
  float* agg = (float*)alloc(sizeof(float) * NN * 64);
  float* x1 = (float*)alloc(sizeof(float) * NN * 64);
  float* x2 = (float*)alloc(sizeof(float) * NN * 64);

  hipMemsetAsync(deg, 0, sizeof(float) * NN, stream);
  hipMemsetAsync(elist, 0xFF, sizeof(int) * ELIST_LEN, stream);

  detect_i64<<<1, 64, 0, stream>>>((const long long*)eidx, flag);
  prep_edges<<<EB, 256, 0, stream>>>(eidx, attr, flag, src, dst, cell, basis, deg, bh);
  scan_offsets<<<1, 1024, 0, stream>>>(bh, blkbase);
  scatter_edges<<<EB, 256, 0, stream>>>(cell, blkbase, elist);

  // layer 0: in=32
  hipMemsetAsync(agg, 0, sizeof(float) * NN * 64, stream);
  edge_mfma<32><<<NBLK_EDGE, 256, 0, stream>>>(x0, w0, elist, cell, src, dst, basis, agg);
  finalize_kernel<32><<<(NN + 3) / 4, 256, 0, stream>>>(x0, agg, deg, root0, b0, x1);

  // layer 1: in=64
  hipMemsetAsync(agg, 0, sizeof(float) * NN * 64, stream);
  edge_mfma<64><<<NBLK_EDGE, 256, 0, stream>>>(x1, w1, elist, cell, src, dst, basis, agg);
  finalize_kernel<64><<<(NN + 3) / 4, 256, 0, stream>>>(x1, agg, deg, root1, b1, x2);

  out_kernel<<<(NN + 3) / 4, 256, 0, stream>>>(x0, x1, x2, fw, fb, out);
}

// Round 4
// 605.984 us; speedup vs baseline: 8.9983x; 1.1358x over previous
//
#include <hip/hip_runtime.h>
#include <hip/hip_bf16.h>
#include <hip/hip_fp16.h>

// SplineCNN forward, MI355X round 4.
// R3 -> R4: rocprof showed edge kernels 87% stalled on the fp32 atomic
// scatter (WRITE_SIZE=200MB = pure atomics, FETCH 168MB = their RMW reads,
// MfmaUtil 4.8%). Replaced atomics with a two-pass dst-sorted reduction:
// edge kernel writes fp16 messages once (plain stores) at dst-sorted
// positions; pass2 reduces each dst's contiguous segment in registers and
// fuses root-GEMV + bias + relu (kills finalize + agg memsets too).
// Fallback to the R3 atomic path if ws_size can't hold the 102MB msg buffer.

typedef __attribute__((ext_vector_type(8))) short short8v;
typedef __attribute__((ext_vector_type(4))) float f32x4;

constexpr int NN = 50000;       // nodes
constexpr int EE = 800000;      // edges
constexpr int CHUNK = 256;      // edges per block in edge_mfma
constexpr int EB = EE / 256;    // 3125 prep/scatter blocks
static_assert(EE % 256 == 0, "prep grid assumes exact divisibility");
constexpr int ELIST_LEN = EE + 16 * CHUNK;
constexpr int NBLK_EDGE = ELIST_LEN / CHUNK;   // 3141

__device__ __forceinline__ short f2bf(float f) {
  return __builtin_bit_cast(short, __float2bfloat16(f));  // RNE
}

// ---------------------------------------------------------------- dtype probe
__global__ void detect_i64(const long long* __restrict__ eidx, int* __restrict__ flag) {
  long long v = eidx[threadIdx.x];
  bool ok = (v >= 0) && (v < (long long)NN);
  unsigned long long m = __ballot(ok);
  if (threadIdx.x == 0) flag[0] = (m == ~0ull) ? 1 : 0;
}

// ------------------------------------------------------------------- prep
__global__ __launch_bounds__(256) void prep_edges(
    const void* __restrict__ eidx, const float* __restrict__ attr,
    const int* __restrict__ flag,
    int* __restrict__ src, int* __restrict__ dst,
    int* __restrict__ cell, float4* __restrict__ basis,
    int* __restrict__ degi, int* __restrict__ bh) {
  __shared__ int wc[4][16];
  const int tid = threadIdx.x;
  const int e = blockIdx.x * 256 + tid;
  int s, d;
  if (flag[0]) {
    s = (int)((const long long*)eidx)[e];
    d = (int)((const long long*)eidx)[EE + e];
  } else {
    s = ((const int*)eidx)[e];
    d = ((const int*)eidx)[EE + e];
  }
  src[e] = s;
  dst[e] = d;
  atomicAdd(&degi[d], 1);
  float v0 = attr[2 * e] * 4.0f, v1 = attr[2 * e + 1] * 4.0f;
  float fl0 = floorf(v0), fl1 = floorf(v1);
  float fr0 = v0 - fl0, fr1 = v1 - fl1;
  int bx = min(max((int)fl0, 0), 3);
  int by = min(max((int)fl1, 0), 3);
  const int c = bx + 4 * by;
  cell[e] = c;
  float4 b;
  b.x = (1.0f - fr0) * (1.0f - fr1);
  b.y = fr0 * (1.0f - fr1);
  b.z = (1.0f - fr0) * fr1;
  b.w = fr0 * fr1;
  basis[e] = b;
  const int wave = tid >> 6, lane = tid & 63;
#pragma unroll
  for (int k = 0; k < 16; ++k) {
    unsigned long long mm = __ballot(c == k);
    if (lane == k) wc[wave][k] = __popcll(mm);
  }
  __syncthreads();
  if (tid < 16)
    bh[blockIdx.x * 16 + tid] = wc[0][tid] + wc[1][tid] + wc[2][tid] + wc[3][tid];
}

// One block, 16 waves: per-cell totals, padded offsets, per-block bases.
__global__ __launch_bounds__(1024) void scan_offsets(
    const int* __restrict__ bh, int* __restrict__ blkbase) {
  __shared__ int tot[16];
  __shared__ int ofs_s[16];
  const int wave = threadIdx.x >> 6, lane = threadIdx.x & 63;
  {
    int sum = 0;
    for (int b = lane; b < EB; b += 64) sum += bh[b * 16 + wave];
#pragma unroll
    for (int off = 32; off > 0; off >>= 1) sum += __shfl_down(sum, off);
    if (lane == 0) tot[wave] = sum;
  }
  __syncthreads();
  if (threadIdx.x == 0) {
    int t = 0;
    for (int c = 0; c < 16; ++c) {
      ofs_s[c] = t;
      t += ((tot[c] + CHUNK - 1) / CHUNK) * CHUNK;
    }
  }
  __syncthreads();
  int running = ofs_s[wave];
  for (int b0 = 0; b0 < EB; b0 += 64) {
    const int b = b0 + lane;
    const int v = (b < EB) ? bh[b * 16 + wave] : 0;
    int inc = v;
#pragma unroll
    for (int off = 1; off < 64; off <<= 1) {
      int n = __shfl_up(inc, off);
      if (lane >= off) inc += n;
    }
    if (b < EB) blkbase[b * 16 + wave] = running + (inc - v);
    running += __shfl(inc, 63);
  }
}

// Exclusive prefix over the 50k degree histogram (one block, 16 waves).
__global__ __launch_bounds__(1024) void scan_deg(
    const int* __restrict__ degi, int* __restrict__ dstbase) {
  __shared__ int wsum[16];
  __shared__ int stot;
  const int wave = threadIdx.x >> 6, lane = threadIdx.x & 63;
  int running = 0;
  for (int base = 0; base < NN; base += 1024) {
    const int i = base + (int)threadIdx.x;
    const int v = (i < NN) ? degi[i] : 0;
    int inc = v;
#pragma unroll
    for (int off = 1; off < 64; off <<= 1) {
      int n = __shfl_up(inc, off);
      if (lane >= off) inc += n;
    }
    if (lane == 63) wsum[wave] = inc;
    __syncthreads();
    if (threadIdx.x == 0) {
      int t = 0;
      for (int w2 = 0; w2 < 16; ++w2) { int tv = wsum[w2]; wsum[w2] = t; t += tv; }
      stot = t;
    }
    __syncthreads();
    if (i < NN) dstbase[i] = running + wsum[wave] + (inc - v);
    running += stot;
    __syncthreads();
  }
}

// Deterministic elist scatter (cell sort) + dst-sorted position assignment.
__global__ __launch_bounds__(256) void scatter_edges(
    const int* __restrict__ cell, const int* __restrict__ blkbase,
    const int* __restrict__ dst, const int* __restrict__ dstbase,
    int* __restrict__ fill2, int* __restrict__ pos,
    int* __restrict__ elist) {
  __shared__ int wc[4][16];
  __shared__ int bs[4][16];
  const int tid = threadIdx.x;
  const int e = blockIdx.x * 256 + tid;
  const int c = cell[e];
  const int wave = tid >> 6, lane = tid & 63;
  int rank = 0;
#pragma unroll
  for (int k = 0; k < 16; ++k) {
    unsigned long long mm = __ballot(c == k);
    if (k == c) rank = __popcll(mm & ((1ull << lane) - 1ull));
    if (lane == k) wc[wave][k] = __popcll(mm);
  }
  const int d = dst[e];
  pos[e] = dstbase[d] + atomicAdd(&fill2[d], 1);
  __syncthreads();
  if (tid < 16) {
    int running = blkbase[blockIdx.x * 16 + tid];
#pragma unroll
    for (int w = 0; w < 4; ++w) { bs[w][tid] = running; running += wc[w][tid]; }
  }
  __syncthreads();
  elist[bs[wave][c] + rank] = e;
}

// ------------------------------------------------------------------- edge msg
// MFMA, CHUNK=256 (4 M-tiles/wave). All tile indices + metadata prefetched
// at wave start (independent loads); x gathered 1 tile ahead.
// TWOPASS: plain fp16 stores to msg[pos[e]]; else fp32 atomics to agg (R3).
template <int IN, bool TWOPASS>
__global__ __launch_bounds__(256) void edge_mfma(
    const float* __restrict__ x, const float* __restrict__ w,
    const int* __restrict__ elist, const int* __restrict__ cellArr,
    const int* __restrict__ src, const int* __restrict__ posArr,
    const float4* __restrict__ basis,
    __half* __restrict__ msg, float* __restrict__ agg) {
  constexpr int K = 4 * IN;
  constexpr int KSTEPS = K / 32;
  constexpr int RS = K * 2;            // LDS row stride bytes
  constexpr int OPR = K / 8;
  constexpr int TILES = CHUNK / 64;    // 4
  __shared__ short8v Wt[64 * OPR];     // bf16 Wcat^T, xor-swizzled
  const int tid = threadIdx.x;
  const int base = blockIdx.x * CHUNK;
  const int e0 = elist[base];
  if (e0 < 0) return;                  // fully-padded chunk (block-uniform)
  {
    const int c = cellArr[e0];
    const int bx = c & 3, by = c >> 2;
    for (int o = tid; o < 64 * OPR; o += 256) {
      const int n = o / OPR;
      const int k0 = (o - n * OPR) * 8;
      const int s = k0 / IN;
      const int i0 = k0 - s * IN;
      const int kk = (bx + (s & 1)) + 5 * (by + (s >> 1));
      const float* wp = w + ((size_t)kk * IN + i0) * 64 + n;
      short8v v;
#pragma unroll
      for (int j = 0; j < 8; ++j) v[j] = f2bf(wp[(size_t)j * 64]);
      const int byte = n * RS + ((k0 * 2) ^ ((n & 15) << 4));
      Wt[byte >> 4] = v;
    }
  }
  __syncthreads();
  const int lane = tid & 63;
  const int wave = tid >> 6;
  const int g = lane >> 4, m = lane & 15;
  const int wbase = base + wave * (CHUNK / 4);
  // prefetch ALL tile indices and per-edge metadata (independent loads)
  int e_t[TILES], row_t[TILES], po_t[TILES];
  float4 bas_t[TILES];
#pragma unroll
  for (int t = 0; t < TILES; ++t) e_t[t] = elist[wbase + t * 16 + m];
#pragma unroll
  for (int t = 0; t < TILES; ++t) {
    const bool v = e_t[t] >= 0;
    const int ei = v ? e_t[t] : 0;
    row_t[t] = v ? src[ei] : 0;
    po_t[t] = v ? posArr[ei] : 0;
    bas_t[t] = v ? basis[ei] : make_float4(0.f, 0.f, 0.f, 0.f);
  }
  // x pipeline, 1 tile deep
  float4 xa_c, xb_c, xc_c = {}, xd_c = {};
  {
    const float4* xr = reinterpret_cast<const float4*>(x + (size_t)row_t[0] * IN);
    xa_c = xr[g * 2];
    xb_c = xr[g * 2 + 1];
    if constexpr (IN == 64) { xc_c = xr[8 + g * 2]; xd_c = xr[8 + g * 2 + 1]; }
  }
#pragma unroll
  for (int t = 0; t < TILES; ++t) {
    float4 xa_n = {}, xb_n = {}, xc_n = {}, xd_n = {};
    if (t + 1 < TILES) {  // issue next gather before compute
      const float4* xr = reinterpret_cast<const float4*>(x + (size_t)row_t[t + 1] * IN);
      xa_n = xr[g * 2];
      xb_n = xr[g * 2 + 1];
      if constexpr (IN == 64) { xc_n = xr[8 + g * 2]; xd_n = xr[8 + g * 2 + 1]; }
    }
    const float xv0[8] = {xa_c.x, xa_c.y, xa_c.z, xa_c.w, xb_c.x, xb_c.y, xb_c.z, xb_c.w};
    const float xv1[8] = {xc_c.x, xc_c.y, xc_c.z, xc_c.w, xd_c.x, xd_c.y, xd_c.z, xd_c.w};
    const float4 bas = bas_t[t];
    f32x4 acc[4];
#pragma unroll
    for (int nt = 0; nt < 4; ++nt) acc[nt] = (f32x4){0.f, 0.f, 0.f, 0.f};
#pragma unroll
    for (int ks = 0; ks < KSTEPS; ++ks) {
      const int s = (IN == 64) ? (ks >> 1) : ks;
      const float bs = (s == 0) ? bas.x : (s == 1) ? bas.y : (s == 2) ? bas.z : bas.w;
      short8v a;
#pragma unroll
      for (int j = 0; j < 8; ++j) {
        const float xf = (IN == 32 || (ks & 1) == 0) ? xv0[j] : xv1[j];
        a[j] = f2bf(bs * xf);
      }
#pragma unroll
      for (int nt = 0; nt < 4; ++nt) {
        const int n = nt * 16 + m;
        const int byte = n * RS + (((ks * 64) + g * 16) ^ ((n & 15) << 4));
        acc[nt] = __builtin_amdgcn_mfma_f32_16x16x32_bf16(a, Wt[byte >> 4], acc[nt], 0, 0, 0);
      }
    }
    // epilogue: D row = edge (lane>>4)*4+r, D col = nt*16 + (lane&15)
#pragma unroll
    for (int r = 0; r < 4; ++r) {
      const int m2 = g * 4 + r;
      const int er = __shfl(e_t[t], m2);
      const int pr = __shfl(po_t[t], m2);
      if (er >= 0) {
        if constexpr (TWOPASS) {
          __half* mp = msg + (size_t)pr * 64 + m;
#pragma unroll
          for (int nt = 0; nt < 4; ++nt) mp[nt * 16] = __float2half_rn(acc[nt][r]);
        } else {
          float* ap = agg + (size_t)pr * 64 + m;
#pragma unroll
          for (int nt = 0; nt < 4; ++nt) atomicAdd(ap + nt * 16, acc[nt][r]);
        }
      }
    }
    xa_c = xa_n; xb_c = xb_n; xc_c = xc_n; xd_c = xd_n;
  }
}

// --------------------------------------------------------------- pass2
// Fused segment-reduce + finalize: one dst per wave. Reads the dst's
// contiguous fp16 message rows (128B coalesced), reduces in fp32, then
// x_out = relu(sum/deg + x_in @ root + bias).
template <int IN>
__global__ __launch_bounds__(256) void pass2_kernel(
    const __half* __restrict__ msg, const int* __restrict__ dstbase,
    const int* __restrict__ degi, const float* __restrict__ x_in,
    const float* __restrict__ root, const float* __restrict__ bias,
    float* __restrict__ x_out) {
  __shared__ float rl[IN * 64];
  __shared__ float xs[4][IN];
  for (int idx = threadIdx.x; idx < IN * 16; idx += 256)
    reinterpret_cast<float4*>(rl)[idx] = reinterpret_cast<const float4*>(root)[idx];
  const int wave = threadIdx.x >> 6, lane = threadIdx.x & 63;
  const int n = blockIdx.x * 4 + wave;   // grid sized so n < NN always
  if (lane < IN / 4)
    reinterpret_cast<float4*>(xs[wave])[lane] =
        reinterpret_cast<const float4*>(x_in + (size_t)n * IN)[lane];
  __syncthreads();
  const int b0 = dstbase[n], dg = degi[n];
  const __half* mp = msg + (size_t)b0 * 64 + lane;
  float acc = 0.f;
  int j = 0;
  for (; j + 4 <= dg; j += 4) {
    const float a0 = __half2float(mp[(size_t)(j + 0) * 64]);
    const float a1 = __half2float(mp[(size_t)(j + 1) * 64]);
    const float a2 = __half2float(mp[(size_t)(j + 2) * 64]);
    const float a3 = __half2float(mp[(size_t)(j + 3) * 64]);
    acc += (a0 + a1) + (a2 + a3);
  }
  for (; j < dg; ++j) acc += __half2float(mp[(size_t)j * 64]);
  float r = acc / fmaxf((float)dg, 1.0f) + bias[lane];
#pragma unroll 8
  for (int i = 0; i < IN; ++i) r = fmaf(xs[wave][i], rl[i * 64 + lane], r);
  x_out[(size_t)n * 64 + lane] = fmaxf(r, 0.0f);
}

// --------------------------------------------------------------- finalize
// (atomic-fallback path only)
template <int IN>
__global__ __launch_bounds__(256) void finalize_kernel(
    const float* __restrict__ x_in, const float* __restrict__ agg,
    const int* __restrict__ degi, const float* __restrict__ root,
    const float* __restrict__ bias, float* __restrict__ x_out) {
  __shared__ float rl[IN * 64];
  for (int idx = threadIdx.x; idx < IN * 16; idx += 256)
    reinterpret_cast<float4*>(rl)[idx] = reinterpret_cast<const float4*>(root)[idx];
  __syncthreads();
  const int wave = threadIdx.x >> 6, lane = threadIdx.x & 63;
  const int n = blockIdx.x * 4 + wave;
  if (n >= NN) return;
  const float d = fmaxf((float)degi[n], 1.0f);
  float r = agg[(size_t)n * 64 + lane] / d + bias[lane];
  const float* xr = x_in + (size_t)n * IN;
#pragma unroll 8
  for (int i = 0; i < IN; ++i) r = fmaf(xr[i], rl[i * 64 + lane], r);
  x_out[(size_t)n * 64 + lane] = fmaxf(r, 0.0f);
}

// ------------------------------------------------------------------- output
__global__ __launch_bounds__(256) void out_kernel(
    const float* __restrict__ x0, const float* __restrict__ x1,
    const float* __restrict__ x2, const float* __restrict__ fw,
    const float* __restrict__ fb, float* __restrict__ out) {
  __shared__ float fl[160 * 64];
  for (int idx = threadIdx.x; idx < 160 * 16; idx += 256)
    reinterpret_cast<float4*>(fl)[idx] = reinterpret_cast<const float4*>(fw)[idx];
  __syncthreads();
  const int wave = threadIdx.x >> 6, lane = threadIdx.x & 63;
  const int n = blockIdx.x * 4 + wave;
  if (n >= NN) return;
  float r = fb[lane];
  const float* a = x0 + (size_t)n * 32;
#pragma unroll 8
  for (int i = 0; i < 32; ++i) r = fmaf(a[i], fl[i * 64 + lane], r);
  const float* b = x1 + (size_t)n * 64;
#pragma unroll 8
  for (int i = 0; i < 64; ++i) r = fmaf(b[i], fl[(32 + i) * 64 + lane], r);
  const float* cx = x2 + (size_t)n * 64;
#pragma unroll 8
  for (int i = 0; i < 64; ++i) r = fmaf(cx[i], fl[(96 + i) * 64 + lane], r);
  out[(size_t)n * 64 + lane] = r;
}

extern "C" void kernel_launch(void* const* d_in, const int* in_sizes, int n_in,
                              void* d_out, int out_size, void* d_ws, size_t ws_size,
                              hipStream_t stream) {
  const float* x0 = (const float*)d_in[0];
  const void* eidx = d_in[1];
  const float* attr = (const float*)d_in[2];
  const float* w0 = (const float*)d_in[3];
  const float* root0 = (const float*)d_in[4];
  const float* b0 = (const float*)d_in[5];
  const float* w1 = (const float*)d_in[6];
  const float* root1 = (const float*)d_in[7];
  const float* b1 = (const float*)d_in[8];
  const float* fw = (const float*)d_in[9];
  const float* fb = (const float*)d_in[10];
  float* out = (float*)d_out;
  (void)in_sizes; (void)n_in; (void)out_size;

  char* wsb = (char*)d_ws;
  size_t off = 0;
  auto alloc = [&](size_t bytes) -> void* {
    void* p = wsb + off;
    off += (bytes + 255) & ~(size_t)255;
    return p;
  };
  int* flag = (int*)alloc(256);
  int* src = (int*)alloc(sizeof(int) * EE);
  int* dst = (int*)alloc(sizeof(int) * EE);
  int* cell = (int*)alloc(sizeof(int) * EE);
  int* pos = (int*)alloc(sizeof(int) * EE);
  float4* basis = (float4*)alloc(sizeof(float4) * EE);
  int* elist = (int*)alloc(sizeof(int) * ELIST_LEN);
  int* degi = (int*)alloc(sizeof(int) * NN);
  int* dstbase = (int*)alloc(sizeof(int) * NN);
  int* fill2 = (int*)alloc(sizeof(int) * NN);
  int* bh = (int*)alloc(sizeof(int) * EB * 16);
  int* blkbase = (int*)alloc(sizeof(int) * EB * 16);
  float* x1 = (float*)alloc(sizeof(float) * NN * 64);
  float* x2 = (float*)alloc(sizeof(float) * NN * 64);
  const size_t common = off;
  const bool twopass = ws_size >= common + sizeof(__half) * (size_t)EE * 64;
  __half* msg = nullptr;
  float* agg = nullptr;
  if (twopass) msg = (__half*)alloc(sizeof(__half) * (size_t)EE * 64);
  else         agg = (float*)alloc(sizeof(float) * (size_t)NN * 64);

  hipMemsetAsync(degi, 0, sizeof(int) * NN, stream);
  hipMemsetAsync(fill2, 0, sizeof(int) * NN, stream);
  hipMemsetAsync(elist, 0xFF, sizeof(int) * ELIST_LEN, stream);

  detect_i64<<<1, 64, 0, stream>>>((const long long*)eidx, flag);
  prep_edges<<<EB, 256, 0, stream>>>(eidx, attr, flag, src, dst, cell, basis, degi, bh);
  scan_offsets<<<1, 1024, 0, stream>>>(bh, blkbase);
  scan_deg<<<1, 1024, 0, stream>>>(degi, dstbase);
  scatter_edges<<<EB, 256, 0, stream>>>(cell, blkbase, dst, dstbase, fill2, pos, elist);

  if (twopass) {
    edge_mfma<32, true><<<NBLK_EDGE, 256, 0, stream>>>(x0, w0, elist, cell, src, pos,
                                                       basis, msg, nullptr);
    pass2_kernel<32><<<NN / 4, 256, 0, stream>>>(msg, dstbase, degi, x0, root0, b0, x1);
    edge_mfma<64, true><<<NBLK_EDGE, 256, 0, stream>>>(x1, w1, elist, cell, src, pos,
                                                       basis, msg, nullptr);
    pass2_kernel<64><<<NN / 4, 256, 0, stream>>>(msg, dstbase, degi, x1, root1, b1, x2);
  } else {
    hipMemsetAsync(agg, 0, sizeof(float) * NN * 64, stream);
    edge_mfma<32, false><<<NBLK_EDGE, 256, 0, stream>>>(x0, w0, elist, cell, src, dst,
                                                        basis, nullptr, agg);
    finalize_kernel<32><<<(NN + 3) / 4, 256, 0, stream>>>(x0, agg, degi, root0, b0, x1);
    hipMemsetAsync(agg, 0, sizeof(float) * NN * 64, stream);
    edge_mfma<64, false><<<NBLK_EDGE, 256, 0, stream>>>(x1, w1, elist, cell, src, dst,
                                                        basis, nullptr, agg);
    finalize_kernel<64><<<(NN + 3) / 4, 256, 0, stream>>>(x1, agg, degi, root1, b1, x2);
  }

  out_kernel<<<(NN + 3) / 4, 256, 0, stream>>>(x0, x1, x2, fw, fb, out);
}

// Round 5
// 591.945 us; speedup vs baseline: 9.2118x; 1.0237x over previous
//
#include <hip/hip_runtime.h>
#include <hip/hip_bf16.h>
#include <hip/hip_fp16.h>

// SplineCNN forward, MI355X round 5.
// R4 -> R5: edge kernels were gather-latency bound (MfmaUtil 6.4%, 1.7TB/s).
// Switch edge datapath to fp16: _Float16 side-copy of x (halves gather bytes),
// K-permuted fragment mapping so each lane's A elements are 1-2 contiguous
// 16B chunks reused across all 4 taps (2 loads/lane/tile instead of 4, and
// basis*x via packed v_pk_mul_f16), f16 MFMA (more mantissa than bf16), and
// all 4 tiles' x prefetched at wave start (deep load pipeline).

typedef __attribute__((ext_vector_type(8))) _Float16 f16x8;
typedef __attribute__((ext_vector_type(4))) float f32x4;

constexpr int NN = 50000;       // nodes
constexpr int EE = 800000;      // edges
constexpr int CHUNK = 256;      // edges per block in edge_mfma
constexpr int EB = EE / 256;    // 3125 prep/scatter blocks
static_assert(EE % 256 == 0, "prep grid assumes exact divisibility");
constexpr int ELIST_LEN = EE + 16 * CHUNK;
constexpr int NBLK_EDGE = ELIST_LEN / CHUNK;   // 3141

// ---------------------------------------------------------------- dtype probe
__global__ void detect_i64(const long long* __restrict__ eidx, int* __restrict__ flag) {
  long long v = eidx[threadIdx.x];
  bool ok = (v >= 0) && (v < (long long)NN);
  unsigned long long m = __ballot(ok);
  if (threadIdx.x == 0) flag[0] = (m == ~0ull) ? 1 : 0;
}

// ------------------------------------------------------------------- prep
__global__ __launch_bounds__(256) void prep_edges(
    const void* __restrict__ eidx, const float* __restrict__ attr,
    const int* __restrict__ flag,
    int* __restrict__ src, int* __restrict__ dst,
    int* __restrict__ cell, float4* __restrict__ basis,
    int* __restrict__ degi, int* __restrict__ bh) {
  __shared__ int wc[4][16];
  const int tid = threadIdx.x;
  const int e = blockIdx.x * 256 + tid;
  int s, d;
  if (flag[0]) {
    s = (int)((const long long*)eidx)[e];
    d = (int)((const long long*)eidx)[EE + e];
  } else {
    s = ((const int*)eidx)[e];
    d = ((const int*)eidx)[EE + e];
  }
  src[e] = s;
  dst[e] = d;
  atomicAdd(&degi[d], 1);
  float v0 = attr[2 * e] * 4.0f, v1 = attr[2 * e + 1] * 4.0f;
  float fl0 = floorf(v0), fl1 = floorf(v1);
  float fr0 = v0 - fl0, fr1 = v1 - fl1;
  int bx = min(max((int)fl0, 0), 3);
  int by = min(max((int)fl1, 0), 3);
  const int c = bx + 4 * by;
  cell[e] = c;
  float4 b;
  b.x = (1.0f - fr0) * (1.0f - fr1);
  b.y = fr0 * (1.0f - fr1);
  b.z = (1.0f - fr0) * fr1;
  b.w = fr0 * fr1;
  basis[e] = b;
  const int wave = tid >> 6, lane = tid & 63;
#pragma unroll
  for (int k = 0; k < 16; ++k) {
    unsigned long long mm = __ballot(c == k);
    if (lane == k) wc[wave][k] = __popcll(mm);
  }
  __syncthreads();
  if (tid < 16)
    bh[blockIdx.x * 16 + tid] = wc[0][tid] + wc[1][tid] + wc[2][tid] + wc[3][tid];
}

// One block, 16 waves: per-cell totals, padded offsets, per-block bases.
__global__ __launch_bounds__(1024) void scan_offsets(
    const int* __restrict__ bh, int* __restrict__ blkbase) {
  __shared__ int tot[16];
  __shared__ int ofs_s[16];
  const int wave = threadIdx.x >> 6, lane = threadIdx.x & 63;
  {
    int sum = 0;
    for (int b = lane; b < EB; b += 64) sum += bh[b * 16 + wave];
#pragma unroll
    for (int off = 32; off > 0; off >>= 1) sum += __shfl_down(sum, off);
    if (lane == 0) tot[wave] = sum;
  }
  __syncthreads();
  if (threadIdx.x == 0) {
    int t = 0;
    for (int c = 0; c < 16; ++c) {
      ofs_s[c] = t;
      t += ((tot[c] + CHUNK - 1) / CHUNK) * CHUNK;
    }
  }
  __syncthreads();
  int running = ofs_s[wave];
  for (int b0 = 0; b0 < EB; b0 += 64) {
    const int b = b0 + lane;
    const int v = (b < EB) ? bh[b * 16 + wave] : 0;
    int inc = v;
#pragma unroll
    for (int off = 1; off < 64; off <<= 1) {
      int n = __shfl_up(inc, off);
      if (lane >= off) inc += n;
    }
    if (b < EB) blkbase[b * 16 + wave] = running + (inc - v);
    running += __shfl(inc, 63);
  }
}

// Exclusive prefix over the 50k degree histogram (one block, 16 waves).
__global__ __launch_bounds__(1024) void scan_deg(
    const int* __restrict__ degi, int* __restrict__ dstbase) {
  __shared__ int wsum[16];
  __shared__ int stot;
  const int wave = threadIdx.x >> 6, lane = threadIdx.x & 63;
  int running = 0;
  for (int base = 0; base < NN; base += 1024) {
    const int i = base + (int)threadIdx.x;
    const int v = (i < NN) ? degi[i] : 0;
    int inc = v;
#pragma unroll
    for (int off = 1; off < 64; off <<= 1) {
      int n = __shfl_up(inc, off);
      if (lane >= off) inc += n;
    }
    if (lane == 63) wsum[wave] = inc;
    __syncthreads();
    if (threadIdx.x == 0) {
      int t = 0;
      for (int w2 = 0; w2 < 16; ++w2) { int tv = wsum[w2]; wsum[w2] = t; t += tv; }
      stot = t;
    }
    __syncthreads();
    if (i < NN) dstbase[i] = running + wsum[wave] + (inc - v);
    running += stot;
    __syncthreads();
  }
}

// Deterministic elist scatter (cell sort) + dst-sorted position assignment.
__global__ __launch_bounds__(256) void scatter_edges(
    const int* __restrict__ cell, const int* __restrict__ blkbase,
    const int* __restrict__ dst, const int* __restrict__ dstbase,
    int* __restrict__ fill2, int* __restrict__ pos,
    int* __restrict__ elist) {
  __shared__ int wc[4][16];
  __shared__ int bs[4][16];
  const int tid = threadIdx.x;
  const int e = blockIdx.x * 256 + tid;
  const int c = cell[e];
  const int wave = tid >> 6, lane = tid & 63;
  int rank = 0;
#pragma unroll
  for (int k = 0; k < 16; ++k) {
    unsigned long long mm = __ballot(c == k);
    if (k == c) rank = __popcll(mm & ((1ull << lane) - 1ull));
    if (lane == k) wc[wave][k] = __popcll(mm);
  }
  const int d = dst[e];
  pos[e] = dstbase[d] + atomicAdd(&fill2[d], 1);
  __syncthreads();
  if (tid < 16) {
    int running = blkbase[blockIdx.x * 16 + tid];
#pragma unroll
    for (int w = 0; w < 4; ++w) { bs[w][tid] = running; running += wc[w][tid]; }
  }
  __syncthreads();
  elist[bs[wave][c] + rank] = e;
}

// ------------------------------------------------------ fp32 -> fp16 convert
template <int LEN8>   // LEN8 = total elems / 8
__global__ __launch_bounds__(256) void f2h_kernel(
    const float* __restrict__ in, _Float16* __restrict__ outh) {
  const int i = blockIdx.x * 256 + threadIdx.x;
  if (i >= LEN8) return;
  const float4 a = reinterpret_cast<const float4*>(in)[i * 2];
  const float4 b = reinterpret_cast<const float4*>(in)[i * 2 + 1];
  f16x8 v = {(_Float16)a.x, (_Float16)a.y, (_Float16)a.z, (_Float16)a.w,
             (_Float16)b.x, (_Float16)b.y, (_Float16)b.z, (_Float16)b.w};
  reinterpret_cast<f16x8*>(outh)[i] = v;
}

// ------------------------------------------------------------------- edge msg
// f16 MFMA, K-permuted so lane (g,m)'s A elements are contiguous 16B chunks
// of the x row, reused across the 4 taps:
//   logical k = ks*32 + g*8 + j  ->  tap s, x index i:
//   IN=32 (KSTEPS=4): s = ks,     i = g*8 + j         (1 chunk/lane)
//   IN=64 (KSTEPS=8): s = ks&3,   i = (ks>>2)*32 + g*8 + j  (2 chunks/lane)
// B[k][n] = W[tap(s)][i][n] staged fp16 in LDS with the same k mapping.
template <int IN, bool TWOPASS>
__global__ __launch_bounds__(256) void edge_mfma(
    const _Float16* __restrict__ xh, const float* __restrict__ w,
    const int* __restrict__ elist, const int* __restrict__ cellArr,
    const int* __restrict__ src, const int* __restrict__ posArr,
    const float4* __restrict__ basis,
    __half* __restrict__ msg, float* __restrict__ agg) {
  constexpr int K = 4 * IN;
  constexpr int KSTEPS = K / 32;
  constexpr int RS = K * 2;            // LDS row stride bytes
  constexpr int OPR = K / 8;           // 16B chunks per row
  constexpr int TILES = CHUNK / 64;    // 4
  constexpr int NCH = (IN == 64) ? 2 : 1;
  __shared__ f16x8 Wt[64 * OPR];       // fp16 Wcat^T (K-permuted), xor-swizzled
  const int tid = threadIdx.x;
  const int base = blockIdx.x * CHUNK;
  const int e0 = elist[base];
  if (e0 < 0) return;                  // fully-padded chunk (block-uniform)
  {
    const int c = cellArr[e0];
    const int bx = c & 3, by = c >> 2;
    for (int o = tid; o < 64 * OPR; o += 256) {
      const int n = o / OPR;
      const int k0 = (o - n * OPR) * 8;
      const int ks = k0 >> 5;
      const int g2 = (k0 & 31) >> 3;
      const int s = (IN == 64) ? (ks & 3) : ks;
      const int i0 = ((IN == 64) ? (ks >> 2) * 32 : 0) + g2 * 8;
      const int kk = (bx + (s & 1)) + 5 * (by + (s >> 1));
      const float* wp = w + ((size_t)kk * IN + i0) * 64 + n;
      f16x8 v;
#pragma unroll
      for (int j = 0; j < 8; ++j) v[j] = (_Float16)wp[(size_t)j * 64];
      const int byte = n * RS + ((k0 * 2) ^ ((n & 15) << 4));
      Wt[byte >> 4] = v;
    }
  }
  __syncthreads();
  const int lane = tid & 63;
  const int wave = tid >> 6;
  const int g = lane >> 4, m = lane & 15;
  const int wbase = base + wave * (CHUNK / 4);
  // prefetch ALL tile indices and per-edge metadata (independent loads)
  int e_t[TILES], row_t[TILES], po_t[TILES];
  float4 bas_t[TILES];
#pragma unroll
  for (int t = 0; t < TILES; ++t) e_t[t] = elist[wbase + t * 16 + m];
#pragma unroll
  for (int t = 0; t < TILES; ++t) {
    const bool v = e_t[t] >= 0;
    const int ei = v ? e_t[t] : 0;
    row_t[t] = v ? src[ei] : 0;
    po_t[t] = v ? posArr[ei] : 0;
    bas_t[t] = v ? basis[ei] : make_float4(0.f, 0.f, 0.f, 0.f);
  }
  // prefetch ALL tiles' x chunks (every gather in flight before first MFMA)
  f16x8 xc[TILES][NCH];
#pragma unroll
  for (int t = 0; t < TILES; ++t) {
    const f16x8* xr = reinterpret_cast<const f16x8*>(xh + (size_t)row_t[t] * IN);
    xc[t][0] = xr[g];
    if constexpr (IN == 64) xc[t][1] = xr[4 + g];
  }
#pragma unroll
  for (int t = 0; t < TILES; ++t) {
    const _Float16 bh[4] = {(_Float16)bas_t[t].x, (_Float16)bas_t[t].y,
                            (_Float16)bas_t[t].z, (_Float16)bas_t[t].w};
    f32x4 acc[4];
#pragma unroll
    for (int nt = 0; nt < 4; ++nt) acc[nt] = (f32x4){0.f, 0.f, 0.f, 0.f};
#pragma unroll
    for (int ks = 0; ks < KSTEPS; ++ks) {
      const int s = (IN == 64) ? (ks & 3) : ks;
      const f16x8 xin = (IN == 64 && (ks >> 2)) ? xc[t][1] : xc[t][0];
      const f16x8 a = xin * bh[s];     // 4x v_pk_mul_f16
#pragma unroll
      for (int nt = 0; nt < 4; ++nt) {
        const int n = nt * 16 + m;
        const int byte = n * RS + (((ks * 64) + g * 16) ^ ((n & 15) << 4));
        acc[nt] = __builtin_amdgcn_mfma_f32_16x16x32_f16(a, Wt[byte >> 4], acc[nt], 0, 0, 0);
      }
    }
    // epilogue: D row = edge (lane>>4)*4+r, D col = nt*16 + (lane&15)
#pragma unroll
    for (int r = 0; r < 4; ++r) {
      const int m2 = g * 4 + r;
      const int er = __shfl(e_t[t], m2);
      const int pr = __shfl(po_t[t], m2);
      if (er >= 0) {
        if constexpr (TWOPASS) {
          __half* mp = msg + (size_t)pr * 64 + m;
#pragma unroll
          for (int nt = 0; nt < 4; ++nt) mp[nt * 16] = __float2half_rn(acc[nt][r]);
        } else {
          float* ap = agg + (size_t)pr * 64 + m;
#pragma unroll
          for (int nt = 0; nt < 4; ++nt) atomicAdd(ap + nt * 16, acc[nt][r]);
        }
      }
    }
  }
}

// --------------------------------------------------------------- pass2
// Fused segment-reduce + finalize: one dst per wave. Also emits the fp16
// side-copy of the output for the next edge kernel's gather.
template <int IN>
__global__ __launch_bounds__(256) void pass2_kernel(
    const __half* __restrict__ msg, const int* __restrict__ dstbase,
    const int* __restrict__ degi, const float* __restrict__ x_in,
    const float* __restrict__ root, const float* __restrict__ bias,
    float* __restrict__ x_out, _Float16* __restrict__ xh_out) {
  __shared__ float rl[IN * 64];
  __shared__ float xs[4][IN];
  for (int idx = threadIdx.x; idx < IN * 16; idx += 256)
    reinterpret_cast<float4*>(rl)[idx] = reinterpret_cast<const float4*>(root)[idx];
  const int wave = threadIdx.x >> 6, lane = threadIdx.x & 63;
  const int n = blockIdx.x * 4 + wave;   // grid sized so n < NN always
  if (lane < IN / 4)
    reinterpret_cast<float4*>(xs[wave])[lane] =
        reinterpret_cast<const float4*>(x_in + (size_t)n * IN)[lane];
  __syncthreads();
  const int b0 = dstbase[n], dg = degi[n];
  const __half* mp = msg + (size_t)b0 * 64 + lane;
  float acc = 0.f;
  int j = 0;
  for (; j + 4 <= dg; j += 4) {
    const float a0 = __half2float(mp[(size_t)(j + 0) * 64]);
    const float a1 = __half2float(mp[(size_t)(j + 1) * 64]);
    const float a2 = __half2float(mp[(size_t)(j + 2) * 64]);
    const float a3 = __half2float(mp[(size_t)(j + 3) * 64]);
    acc += (a0 + a1) + (a2 + a3);
  }
  for (; j < dg; ++j) acc += __half2float(mp[(size_t)j * 64]);
  float r = acc / fmaxf((float)dg, 1.0f) + bias[lane];
#pragma unroll 8
  for (int i = 0; i < IN; ++i) r = fmaf(xs[wave][i], rl[i * 64 + lane], r);
  r = fmaxf(r, 0.0f);
  x_out[(size_t)n * 64 + lane] = r;
  xh_out[(size_t)n * 64 + lane] = (_Float16)r;
}

// --------------------------------------------------------------- finalize
// (atomic-fallback path only)
template <int IN>
__global__ __launch_bounds__(256) void finalize_kernel(
    const float* __restrict__ x_in, const float* __restrict__ agg,
    const int* __restrict__ degi, const float* __restrict__ root,
    const float* __restrict__ bias, float* __restrict__ x_out,
    _Float16* __restrict__ xh_out) {
  __shared__ float rl[IN * 64];
  for (int idx = threadIdx.x; idx < IN * 16; idx += 256)
    reinterpret_cast<float4*>(rl)[idx] = reinterpret_cast<const float4*>(root)[idx];
  __syncthreads();
  const int wave = threadIdx.x >> 6, lane = threadIdx.x & 63;
  const int n = blockIdx.x * 4 + wave;
  if (n >= NN) return;
  const float d = fmaxf((float)degi[n], 1.0f);
  float r = agg[(size_t)n * 64 + lane] / d + bias[lane];
  const float* xr = x_in + (size_t)n * IN;
#pragma unroll 8
  for (int i = 0; i < IN; ++i) r = fmaf(xr[i], rl[i * 64 + lane], r);
  r = fmaxf(r, 0.0f);
  x_out[(size_t)n * 64 + lane] = r;
  xh_out[(size_t)n * 64 + lane] = (_Float16)r;
}

// ------------------------------------------------------------------- output
__global__ __launch_bounds__(256) void out_kernel(
    const float* __restrict__ x0, const float* __restrict__ x1,
    const float* __restrict__ x2, const float* __restrict__ fw,
    const float* __restrict__ fb, float* __restrict__ out) {
  __shared__ float fl[160 * 64];
  for (int idx = threadIdx.x; idx < 160 * 16; idx += 256)
    reinterpret_cast<float4*>(fl)[idx] = reinterpret_cast<const float4*>(fw)[idx];
  __syncthreads();
  const int wave = threadIdx.x >> 6, lane = threadIdx.x & 63;
  const int n = blockIdx.x * 4 + wave;
  if (n >= NN) return;
  float r = fb[lane];
  const float* a = x0 + (size_t)n * 32;
#pragma unroll 8
  for (int i = 0; i < 32; ++i) r = fmaf(a[i], fl[i * 64 + lane], r);
  const float* b = x1 + (size_t)n * 64;
#pragma unroll 8
  for (int i = 0; i < 64; ++i) r = fmaf(b[i], fl[(32 + i) * 64 + lane], r);
  const float* cx = x2 + (size_t)n * 64;
#pragma unroll 8
  for (int i = 0; i < 64; ++i) r = fmaf(cx[i], fl[(96 + i) * 64 + lane], r);
  out[(size_t)n * 64 + lane] = r;
}

extern "C" void kernel_launch(void* const* d_in, const int* in_sizes, int n_in,
                              void* d_out, int out_size, void* d_ws, size_t ws_size,
                              hipStream_t stream) {
  const float* x0 = (const float*)d_in[0];
  const void* eidx = d_in[1];
  const float* attr = (const float*)d_in[2];
  const float* w0 = (const float*)d_in[3];
  const float* root0 = (const float*)d_in[4];
  const float* b0 = (const float*)d_in[5];
  const float* w1 = (const float*)d_in[6];
  const float* root1 = (const float*)d_in[7];
  const float* b1 = (const float*)d_in[8];
  const float* fw = (const float*)d_in[9];
  const float* fb = (const float*)d_in[10];
  float* out = (float*)d_out;
  (void)in_sizes; (void)n_in; (void)out_size;

  char* wsb = (char*)d_ws;
  size_t off = 0;
  auto alloc = [&](size_t bytes) -> void* {
    void* p = wsb + off;
    off += (bytes + 255) & ~(size_t)255;
    return p;
  };
  int* flag = (int*)alloc(256);
  int* src = (int*)alloc(sizeof(int) * EE);
  int* dst = (int*)alloc(sizeof(int) * EE);
  int* cell = (int*)alloc(sizeof(int) * EE);
  int* pos = (int*)alloc(sizeof(int) * EE);
  float4* basis = (float4*)alloc(sizeof(float4) * EE);
  int* elist = (int*)alloc(sizeof(int) * ELIST_LEN);
  int* degi = (int*)alloc(sizeof(int) * NN);
  int* dstbase = (int*)alloc(sizeof(int) * NN);
  int* fill2 = (int*)alloc(sizeof(int) * NN);
  int* bh = (int*)alloc(sizeof(int) * EB * 16);
  int* blkbase = (int*)alloc(sizeof(int) * EB * 16);
  float* x1 = (float*)alloc(sizeof(float) * NN * 64);
  float* x2 = (float*)alloc(sizeof(float) * NN * 64);
  _Float16* xh0 = (_Float16*)alloc(sizeof(_Float16) * NN * 32);
  _Float16* xh1 = (_Float16*)alloc(sizeof(_Float16) * NN * 64);
  const size_t common = off;
  const bool twopass = ws_size >= common + sizeof(__half) * (size_t)EE * 64;
  __half* msg = nullptr;
  float* agg = nullptr;
  if (twopass) msg = (__half*)alloc(sizeof(__half) * (size_t)EE * 64);
  else         agg = (float*)alloc(sizeof(float) * (size_t)NN * 64);

  hipMemsetAsync(degi, 0, sizeof(int) * NN, stream);
  hipMemsetAsync(fill2, 0, sizeof(int) * NN, stream);
  hipMemsetAsync(elist, 0xFF, sizeof(int) * ELIST_LEN, stream);

  detect_i64<<<1, 64, 0, stream>>>((const long long*)eidx, flag);
  prep_edges<<<EB, 256, 0, stream>>>(eidx, attr, flag, src, dst, cell, basis, degi, bh);
  scan_offsets<<<1, 1024, 0, stream>>>(bh, blkbase);
  scan_deg<<<1, 1024, 0, stream>>>(degi, dstbase);
  scatter_edges<<<EB, 256, 0, stream>>>(cell, blkbase, dst, dstbase, fill2, pos, elist);
  constexpr int L0_8 = NN * 32 / 8;
  f2h_kernel<L0_8><<<(L0_8 + 255) / 256, 256, 0, stream>>>(x0, xh0);

  if (twopass) {
    edge_mfma<32, true><<<NBLK_EDGE, 256, 0, stream>>>(xh0, w0, elist, cell, src, pos,
                                                       basis, msg, nullptr);
    pass2_kernel<32><<<NN / 4, 256, 0, stream>>>(msg, dstbase, degi, x0, root0, b0, x1, xh1);
    edge_mfma<64, true><<<NBLK_EDGE, 256, 0, stream>>>(xh1, w1, elist, cell, src, pos,
                                                       basis, msg, nullptr);
    pass2_kernel<64><<<NN / 4, 256, 0, stream>>>(msg, dstbase, degi, x1, root1, b1, x2, xh1);
  } else {
    hipMemsetAsync(agg, 0, sizeof(float) * NN * 64, stream);
    edge_mfma<32, false><<<NBLK_EDGE, 256, 0, stream>>>(xh0, w0, elist, cell, src, dst,
                                                        basis, nullptr, agg);
    finalize_kernel<32><<<(NN + 3) / 4, 256, 0, stream>>>(x0, agg, degi, root0, b0, x1, xh1);
    hipMemsetAsync(agg, 0, sizeof(float) * NN * 64, stream);
    edge_mfma<64, false><<<NBLK_EDGE, 256, 0, stream>>>(xh1, w1, elist, cell, src, dst,
                                                        basis, nullptr, agg);
    finalize_kernel<64><<<(NN + 3) / 4, 256, 0, stream>>>(x1, agg, degi, root1, b1, x2, xh1);
  }

  out_kernel<<<(NN + 3) / 4, 256, 0, stream>>>(x0, x1, x2, fw, fb, out);
}

// Round 6
// 460.670 us; speedup vs baseline: 11.8368x; 1.2850x over previous
//
#include <hip/hip_runtime.h>
#include <hip/hip_bf16.h>
#include <hip/hip_fp16.h>

// SplineCNN forward, MI355X round 6.
// R5 -> R6: edge kernels were latency-bound (MfmaUtil 7%, VALUBusy 9%,
// HBM 19%): per-block W staging was 16384 uncoalesced 4B strided loads, and
// metadata was a 3-hop dependent chain (elist -> src/pos/basis -> x).
// Now: per-cell W images precomputed ONCE (f16, K-permuted, swizzle baked in)
// so block staging is a linear coalesced copy; scatter emits pre-sorted
// srcS/posS/basS so the edge kernel has a single dependent hop (srcS -> x);
// msg rows permuted (m*4+nt) so epilogue stores are 8B instead of 4x2B.

typedef __attribute__((ext_vector_type(8))) _Float16 f16x8;
typedef __attribute__((ext_vector_type(4))) _Float16 f16x4;
typedef __attribute__((ext_vector_type(4))) float f32x4;

constexpr int NN = 50000;       // nodes
constexpr int EE = 800000;      // edges
constexpr int CHUNK = 256;      // edges per block in edge_mfma
constexpr int EB = EE / 256;    // 3125 prep/scatter blocks
static_assert(EE % 256 == 0, "prep grid assumes exact divisibility");
constexpr int ELIST_LEN = EE + 16 * CHUNK;
constexpr int NBLK_EDGE = ELIST_LEN / CHUNK;   // 3141

// ---------------------------------------------------------------- dtype probe
__global__ void detect_i64(const long long* __restrict__ eidx, int* __restrict__ flag) {
  long long v = eidx[threadIdx.x];
  bool ok = (v >= 0) && (v < (long long)NN);
  unsigned long long m = __ballot(ok);
  if (threadIdx.x == 0) flag[0] = (m == ~0ull) ? 1 : 0;
}

// ------------------------------------------------------------------- prep
__global__ __launch_bounds__(256) void prep_edges(
    const void* __restrict__ eidx, const float* __restrict__ attr,
    const int* __restrict__ flag,
    int* __restrict__ src, int* __restrict__ dst,
    int* __restrict__ cell, float4* __restrict__ basis,
    int* __restrict__ degi, int* __restrict__ bh) {
  __shared__ int wc[4][16];
  const int tid = threadIdx.x;
  const int e = blockIdx.x * 256 + tid;
  int s, d;
  if (flag[0]) {
    s = (int)((const long long*)eidx)[e];
    d = (int)((const long long*)eidx)[EE + e];
  } else {
    s = ((const int*)eidx)[e];
    d = ((const int*)eidx)[EE + e];
  }
  src[e] = s;
  dst[e] = d;
  atomicAdd(&degi[d], 1);
  float v0 = attr[2 * e] * 4.0f, v1 = attr[2 * e + 1] * 4.0f;
  float fl0 = floorf(v0), fl1 = floorf(v1);
  float fr0 = v0 - fl0, fr1 = v1 - fl1;
  int bx = min(max((int)fl0, 0), 3);
  int by = min(max((int)fl1, 0), 3);
  const int c = bx + 4 * by;
  cell[e] = c;
  float4 b;
  b.x = (1.0f - fr0) * (1.0f - fr1);
  b.y = fr0 * (1.0f - fr1);
  b.z = (1.0f - fr0) * fr1;
  b.w = fr0 * fr1;
  basis[e] = b;
  const int wave = tid >> 6, lane = tid & 63;
#pragma unroll
  for (int k = 0; k < 16; ++k) {
    unsigned long long mm = __ballot(c == k);
    if (lane == k) wc[wave][k] = __popcll(mm);
  }
  __syncthreads();
  if (tid < 16)
    bh[blockIdx.x * 16 + tid] = wc[0][tid] + wc[1][tid] + wc[2][tid] + wc[3][tid];
}

// One block, 16 waves: per-cell totals, padded offsets, per-block bases,
// and the chunk -> cell map for the edge kernel grid.
__global__ __launch_bounds__(1024) void scan_offsets(
    const int* __restrict__ bh, int* __restrict__ blkbase,
    int* __restrict__ chunkcell) {
  __shared__ int tot[16];
  __shared__ int ofs_s[16];
  const int wave = threadIdx.x >> 6, lane = threadIdx.x & 63;
  {
    int sum = 0;
    for (int b = lane; b < EB; b += 64) sum += bh[b * 16 + wave];
#pragma unroll
    for (int off = 32; off > 0; off >>= 1) sum += __shfl_down(sum, off);
    if (lane == 0) tot[wave] = sum;
  }
  __syncthreads();
  if (threadIdx.x == 0) {
    int t = 0;
    for (int c = 0; c < 16; ++c) {
      ofs_s[c] = t;
      t += ((tot[c] + CHUNK - 1) / CHUNK) * CHUNK;
    }
  }
  __syncthreads();
  {  // chunk -> cell map (wave w owns cell w); padding chunks get -1
    const int nch = (tot[wave] + CHUNK - 1) / CHUNK;
    const int cb = ofs_s[wave] / CHUNK;
    for (int i = lane; i < nch; i += 64) chunkcell[cb + i] = wave;
    if (wave == 15) {
      const int totch = cb + nch;
      for (int i = totch + lane; i < NBLK_EDGE; i += 64) chunkcell[i] = -1;
    }
  }
  int running = ofs_s[wave];
  for (int b0 = 0; b0 < EB; b0 += 64) {
    const int b = b0 + lane;
    const int v = (b < EB) ? bh[b * 16 + wave] : 0;
    int inc = v;
#pragma unroll
    for (int off = 1; off < 64; off <<= 1) {
      int n = __shfl_up(inc, off);
      if (lane >= off) inc += n;
    }
    if (b < EB) blkbase[b * 16 + wave] = running + (inc - v);
    running += __shfl(inc, 63);
  }
}

// Exclusive prefix over the 50k degree histogram (one block, 16 waves).
__global__ __launch_bounds__(1024) void scan_deg(
    const int* __restrict__ degi, int* __restrict__ dstbase) {
  __shared__ int wsum[16];
  __shared__ int stot;
  const int wave = threadIdx.x >> 6, lane = threadIdx.x & 63;
  int running = 0;
  for (int base = 0; base < NN; base += 1024) {
    const int i = base + (int)threadIdx.x;
    const int v = (i < NN) ? degi[i] : 0;
    int inc = v;
#pragma unroll
    for (int off = 1; off < 64; off <<= 1) {
      int n = __shfl_up(inc, off);
      if (lane >= off) inc += n;
    }
    if (lane == 63) wsum[wave] = inc;
    __syncthreads();
    if (threadIdx.x == 0) {
      int t = 0;
      for (int w2 = 0; w2 < 16; ++w2) { int tv = wsum[w2]; wsum[w2] = t; t += tv; }
      stot = t;
    }
    __syncthreads();
    if (i < NN) dstbase[i] = running + wsum[wave] + (inc - v);
    running += stot;
    __syncthreads();
  }
}

// Deterministic cell-sorted scatter of ALL per-edge metadata:
// srcS/posS/basS[p] hold src row, dst-sorted msg position, basis for the
// edge at sorted position p. Removes one indirection from the edge kernel.
__global__ __launch_bounds__(256) void scatter_edges(
    const int* __restrict__ cell, const int* __restrict__ blkbase,
    const int* __restrict__ srcArr, const int* __restrict__ dst,
    const float4* __restrict__ basis, const int* __restrict__ dstbase,
    int* __restrict__ fill2,
    int* __restrict__ srcS, int* __restrict__ posS, float4* __restrict__ basS) {
  __shared__ int wc[4][16];
  __shared__ int bs[4][16];
  const int tid = threadIdx.x;
  const int e = blockIdx.x * 256 + tid;
  const int c = cell[e];
  const int wave = tid >> 6, lane = tid & 63;
  int rank = 0;
#pragma unroll
  for (int k = 0; k < 16; ++k) {
    unsigned long long mm = __ballot(c == k);
    if (k == c) rank = __popcll(mm & ((1ull << lane) - 1ull));
    if (lane == k) wc[wave][k] = __popcll(mm);
  }
  const int d = dst[e];
  const int mypos = dstbase[d] + atomicAdd(&fill2[d], 1);
  __syncthreads();
  if (tid < 16) {
    int running = blkbase[blockIdx.x * 16 + tid];
#pragma unroll
    for (int w = 0; w < 4; ++w) { bs[w][tid] = running; running += wc[w][tid]; }
  }
  __syncthreads();
  const int p = bs[wave][c] + rank;
  srcS[p] = srcArr[e];
  posS[p] = mypos;
  basS[p] = basis[e];
}

// ------------------------------------------------------ fp32 -> fp16 convert
template <int LEN8>   // LEN8 = total elems / 8
__global__ __launch_bounds__(256) void f2h_kernel(
    const float* __restrict__ in, _Float16* __restrict__ outh) {
  const int i = blockIdx.x * 256 + threadIdx.x;
  if (i >= LEN8) return;
  const float4 a = reinterpret_cast<const float4*>(in)[i * 2];
  const float4 b = reinterpret_cast<const float4*>(in)[i * 2 + 1];
  f16x8 v = {(_Float16)a.x, (_Float16)a.y, (_Float16)a.z, (_Float16)a.w,
             (_Float16)b.x, (_Float16)b.y, (_Float16)b.z, (_Float16)b.w};
  reinterpret_cast<f16x8*>(outh)[i] = v;
}

// ----------------------------------------------------- per-cell W images
// Build the exact LDS image per cell ONCE: f16, K-permuted, xor-swizzled.
// Pays the strided w reads 16x total instead of 3141x.
template <int IN>
__global__ __launch_bounds__(256) void conv_w_kernel(
    const float* __restrict__ w, _Float16* __restrict__ wcell) {
  constexpr int K = 4 * IN;
  constexpr int RS = K * 2;
  constexpr int OPR = K / 8;
  const int c = blockIdx.y;
  const int o = blockIdx.x * 256 + threadIdx.x;   // < 64*OPR
  const int bx = c & 3, by = c >> 2;
  const int n = o / OPR;
  const int k0 = (o - n * OPR) * 8;
  const int ks = k0 >> 5;
  const int g2 = (k0 & 31) >> 3;
  const int s = (IN == 64) ? (ks & 3) : ks;
  const int i0 = ((IN == 64) ? (ks >> 2) * 32 : 0) + g2 * 8;
  const int kk = (bx + (s & 1)) + 5 * (by + (s >> 1));
  const float* wp = w + ((size_t)kk * IN + i0) * 64 + n;
  f16x8 v;
#pragma unroll
  for (int j = 0; j < 8; ++j) v[j] = (_Float16)wp[(size_t)j * 64];
  const int byte = n * RS + ((k0 * 2) ^ ((n & 15) << 4));
  *reinterpret_cast<f16x8*>(
      reinterpret_cast<char*>(wcell) + (size_t)c * (RS * 64) + byte) = v;
}

// ------------------------------------------------------------------- edge msg
// f16 MFMA. Staging = linear coalesced copy of the cell's prebuilt image.
// Metadata = direct coalesced loads from sorted arrays (1 dependent hop to x).
// K-permuted mapping (same as R5): lane (g,m), k = ks*32 + g*8 + j.
template <int IN, bool TWOPASS>
__global__ __launch_bounds__(256) void edge_mfma(
    const _Float16* __restrict__ xh, const _Float16* __restrict__ wcell,
    const int* __restrict__ chunkcell,
    const int* __restrict__ srcS, const int* __restrict__ posS,
    const float4* __restrict__ basS,
    __half* __restrict__ msg, float* __restrict__ agg) {
  constexpr int K = 4 * IN;
  constexpr int KSTEPS = K / 32;
  constexpr int RS = K * 2;            // LDS row stride bytes
  constexpr int OPR = K / 8;           // 16B chunks per row
  constexpr int TILES = CHUNK / 64;    // 4
  constexpr int NCH = (IN == 64) ? 2 : 1;
  __shared__ f16x8 Wt[64 * OPR];
  const int tid = threadIdx.x;
  const int c = chunkcell[blockIdx.x];
  if (c < 0) return;                   // fully-padded chunk
  const int base = blockIdx.x * CHUNK;
  const int lane = tid & 63;
  const int wave = tid >> 6;
  const int g = lane >> 4, m = lane & 15;
  const int wbase = base + wave * (CHUNK / 4);
  // metadata prefetch: independent coalesced loads, issued before staging
  int sv_t[TILES], po_t[TILES];
  float4 bas_t[TILES];
#pragma unroll
  for (int t = 0; t < TILES; ++t) sv_t[t] = srcS[wbase + t * 16 + m];
#pragma unroll
  for (int t = 0; t < TILES; ++t) po_t[t] = posS[wbase + t * 16 + m];
#pragma unroll
  for (int t = 0; t < TILES; ++t) bas_t[t] = basS[wbase + t * 16 + m];
  // stage the prebuilt cell image: linear coalesced 16B copies
  {
    const f16x8* gw = reinterpret_cast<const f16x8*>(wcell) + (size_t)c * (64 * OPR);
    for (int o = tid; o < 64 * OPR; o += 256) Wt[o] = gw[o];
  }
  __syncthreads();
  // x gather (single dependent hop), all tiles in flight together
  f16x8 xc[TILES][NCH];
#pragma unroll
  for (int t = 0; t < TILES; ++t) {
    const int row = (sv_t[t] >= 0) ? sv_t[t] : 0;
    const f16x8* xr = reinterpret_cast<const f16x8*>(xh + (size_t)row * IN);
    xc[t][0] = xr[g];
    if constexpr (IN == 64) xc[t][1] = xr[4 + g];
  }
#pragma unroll
  for (int t = 0; t < TILES; ++t) {
    const _Float16 bhv[4] = {(_Float16)bas_t[t].x, (_Float16)bas_t[t].y,
                             (_Float16)bas_t[t].z, (_Float16)bas_t[t].w};
    f32x4 acc[4];
#pragma unroll
    for (int nt = 0; nt < 4; ++nt) acc[nt] = (f32x4){0.f, 0.f, 0.f, 0.f};
#pragma unroll
    for (int ks = 0; ks < KSTEPS; ++ks) {
      const int s = (IN == 64) ? (ks & 3) : ks;
      const f16x8 xin = (IN == 64 && (ks >> 2)) ? xc[t][1] : xc[t][0];
      const f16x8 a = xin * bhv[s];    // packed f16 mul
#pragma unroll
      for (int nt = 0; nt < 4; ++nt) {
        const int n = nt * 16 + m;
        const int byte = n * RS + (((ks * 64) + g * 16) ^ ((n & 15) << 4));
        acc[nt] = __builtin_amdgcn_mfma_f32_16x16x32_f16(a, Wt[byte >> 4], acc[nt], 0, 0, 0);
      }
    }
    // epilogue: D row = edge (lane>>4)*4+r, D col = nt*16 + (lane&15).
    // TWOPASS msg row layout is PERMUTED: channel nt*16+m stored at m*4+nt,
    // so each lane writes one 8B chunk. pass2 reads with the inverse index.
#pragma unroll
    for (int r = 0; r < 4; ++r) {
      const int m2 = g * 4 + r;
      const int er = __shfl(sv_t[t], m2);
      const int pr = __shfl(po_t[t], m2);
      if (er >= 0) {
        if constexpr (TWOPASS) {
          f16x4 pv = {(_Float16)acc[0][r], (_Float16)acc[1][r],
                      (_Float16)acc[2][r], (_Float16)acc[3][r]};
          *reinterpret_cast<f16x4*>(msg + (size_t)pr * 64 + m * 4) = pv;
        } else {
          float* ap = agg + (size_t)pr * 64 + m;
#pragma unroll
          for (int nt = 0; nt < 4; ++nt) atomicAdd(ap + nt * 16, acc[nt][r]);
        }
      }
    }
  }
}

// --------------------------------------------------------------- pass2
// Fused segment-reduce + finalize; msg rows are permuted (see edge epilogue).
template <int IN>
__global__ __launch_bounds__(256) void pass2_kernel(
    const __half* __restrict__ msg, const int* __restrict__ dstbase,
    const int* __restrict__ degi, const float* __restrict__ x_in,
    const float* __restrict__ root, const float* __restrict__ bias,
    float* __restrict__ x_out, _Float16* __restrict__ xh_out) {
  __shared__ float rl[IN * 64];
  __shared__ float xs[4][IN];
  for (int idx = threadIdx.x; idx < IN * 16; idx += 256)
    reinterpret_cast<float4*>(rl)[idx] = reinterpret_cast<const float4*>(root)[idx];
  const int wave = threadIdx.x >> 6, lane = threadIdx.x & 63;
  const int n = blockIdx.x * 4 + wave;   // grid sized so n < NN always
  if (lane < IN / 4)
    reinterpret_cast<float4*>(xs[wave])[lane] =
        reinterpret_cast<const float4*>(x_in + (size_t)n * IN)[lane];
  __syncthreads();
  const int b0 = dstbase[n], dg = degi[n];
  // channel `lane` lives at permuted position (lane&15)*4 + (lane>>4)
  const __half* mp = msg + (size_t)b0 * 64 + ((lane & 15) * 4 + (lane >> 4));
  float acc = 0.f;
  int j = 0;
  for (; j + 4 <= dg; j += 4) {
    const float a0 = __half2float(mp[(size_t)(j + 0) * 64]);
    const float a1 = __half2float(mp[(size_t)(j + 1) * 64]);
    const float a2 = __half2float(mp[(size_t)(j + 2) * 64]);
    const float a3 = __half2float(mp[(size_t)(j + 3) * 64]);
    acc += (a0 + a1) + (a2 + a3);
  }
  for (; j < dg; ++j) acc += __half2float(mp[(size_t)j * 64]);
  float r = acc / fmaxf((float)dg, 1.0f) + bias[lane];
#pragma unroll 8
  for (int i = 0; i < IN; ++i) r = fmaf(xs[wave][i], rl[i * 64 + lane], r);
  r = fmaxf(r, 0.0f);
  x_out[(size_t)n * 64 + lane] = r;
  xh_out[(size_t)n * 64 + lane] = (_Float16)r;
}

// --------------------------------------------------------------- finalize
// (atomic-fallback path only)
template <int IN>
__global__ __launch_bounds__(256) void finalize_kernel(
    const float* __restrict__ x_in, const float* __restrict__ agg,
    const int* __restrict__ degi, const float* __restrict__ root,
    const float* __restrict__ bias, float* __restrict__ x_out,
    _Float16* __restrict__ xh_out) {
  __shared__ float rl[IN * 64];
  for (int idx = threadIdx.x; idx < IN * 16; idx += 256)
    reinterpret_cast<float4*>(rl)[idx] = reinterpret_cast<const float4*>(root)[idx];
  __syncthreads();
  const int wave = threadIdx.x >> 6, lane = threadIdx.x & 63;
  const int n = blockIdx.x * 4 + wave;
  if (n >= NN) return;
  const float d = fmaxf((float)degi[n], 1.0f);
  float r = agg[(size_t)n * 64 + lane] / d + bias[lane];
  const float* xr = x_in + (size_t)n * IN;
#pragma unroll 8
  for (int i = 0; i < IN; ++i) r = fmaf(xr[i], rl[i * 64 + lane], r);
  r = fmaxf(r, 0.0f);
  x_out[(size_t)n * 64 + lane] = r;
  xh_out[(size_t)n * 64 + lane] = (_Float16)r;
}

// ------------------------------------------------------------------- output
__global__ __launch_bounds__(256) void out_kernel(
    const float* __restrict__ x0, const float* __restrict__ x1,
    const float* __restrict__ x2, const float* __restrict__ fw,
    const float* __restrict__ fb, float* __restrict__ out) {
  __shared__ float fl[160 * 64];
  for (int idx = threadIdx.x; idx < 160 * 16; idx += 256)
    reinterpret_cast<float4*>(fl)[idx] = reinterpret_cast<const float4*>(fw)[idx];
  __syncthreads();
  const int wave = threadIdx.x >> 6, lane = threadIdx.x & 63;
  const int n = blockIdx.x * 4 + wave;
  if (n >= NN) return;
  float r = fb[lane];
  const float* a = x0 + (size_t)n * 32;
#pragma unroll 8
  for (int i = 0; i < 32; ++i) r = fmaf(a[i], fl[i * 64 + lane], r);
  const float* b = x1 + (size_t)n * 64;
#pragma unroll 8
  for (int i = 0; i < 64; ++i) r = fmaf(b[i], fl[(32 + i) * 64 + lane], r);
  const float* cx = x2 + (size_t)n * 64;
#pragma unroll 8
  for (int i = 0; i < 64; ++i) r = fmaf(cx[i], fl[(96 + i) * 64 + lane], r);
  out[(size_t)n * 64 + lane] = r;
}

extern "C" void kernel_launch(void* const* d_in, const int* in_sizes, int n_in,
                              void* d_out, int out_size, void* d_ws, size_t ws_size,
                              hipStream_t stream) {
  const float* x0 = (const float*)d_in[0];
  const void* eidx = d_in[1];
  const float* attr = (const float*)d_in[2];
  const float* w0 = (const float*)d_in[3];
  const float* root0 = (const float*)d_in[4];
  const float* b0 = (const float*)d_in[5];
  const float* w1 = (const float*)d_in[6];
  const float* root1 = (const float*)d_in[7];
  const float* b1 = (const float*)d_in[8];
  const float* fw = (const float*)d_in[9];
  const float* fb = (const float*)d_in[10];
  float* out = (float*)d_out;
  (void)in_sizes; (void)n_in; (void)out_size;

  char* wsb = (char*)d_ws;
  size_t off = 0;
  auto alloc = [&](size_t bytes) -> void* {
    void* p = wsb + off;
    off += (bytes + 255) & ~(size_t)255;
    return p;
  };
  int* flag = (int*)alloc(256);
  int* src = (int*)alloc(sizeof(int) * EE);
  int* dst = (int*)alloc(sizeof(int) * EE);
  int* cell = (int*)alloc(sizeof(int) * EE);
  float4* basis = (float4*)alloc(sizeof(float4) * EE);
  int* srcS = (int*)alloc(sizeof(int) * ELIST_LEN);
  int* posS = (int*)alloc(sizeof(int) * ELIST_LEN);
  float4* basS = (float4*)alloc(sizeof(float4) * ELIST_LEN);
  int* chunkcell = (int*)alloc(sizeof(int) * NBLK_EDGE);
  int* degi = (int*)alloc(sizeof(int) * NN);
  int* dstbase = (int*)alloc(sizeof(int) * NN);
  int* fill2 = (int*)alloc(sizeof(int) * NN);
  int* bh = (int*)alloc(sizeof(int) * EB * 16);
  int* blkbase = (int*)alloc(sizeof(int) * EB * 16);
  float* x1 = (float*)alloc(sizeof(float) * NN * 64);
  float* x2 = (float*)alloc(sizeof(float) * NN * 64);
  _Float16* xh0 = (_Float16*)alloc(sizeof(_Float16) * NN * 32);
  _Float16* xh1 = (_Float16*)alloc(sizeof(_Float16) * NN * 64);
  _Float16* wc0 = (_Float16*)alloc(sizeof(_Float16) * 16 * 128 * 64);  // 256KB
  _Float16* wc1 = (_Float16*)alloc(sizeof(_Float16) * 16 * 256 * 64);  // 512KB
  const size_t common = off;
  const bool twopass = ws_size >= common + sizeof(__half) * (size_t)EE * 64;
  __half* msg = nullptr;
  float* agg = nullptr;
  if (twopass) msg = (__half*)alloc(sizeof(__half) * (size_t)EE * 64);
  else         agg = (float*)alloc(sizeof(float) * (size_t)NN * 64);

  hipMemsetAsync(degi, 0, sizeof(int) * NN, stream);
  hipMemsetAsync(fill2, 0, sizeof(int) * NN, stream);
  hipMemsetAsync(srcS, 0xFF, sizeof(int) * ELIST_LEN, stream);  // -1 sentinels

  detect_i64<<<1, 64, 0, stream>>>((const long long*)eidx, flag);
  prep_edges<<<EB, 256, 0, stream>>>(eidx, attr, flag, src, dst, cell, basis, degi, bh);
  scan_offsets<<<1, 1024, 0, stream>>>(bh, blkbase, chunkcell);
  scan_deg<<<1, 1024, 0, stream>>>(degi, dstbase);
  scatter_edges<<<EB, 256, 0, stream>>>(cell, blkbase, src, dst, basis, dstbase,
                                        fill2, srcS, posS, basS);
  constexpr int L0_8 = NN * 32 / 8;
  f2h_kernel<L0_8><<<(L0_8 + 255) / 256, 256, 0, stream>>>(x0, xh0);
  conv_w_kernel<32><<<dim3(4, 16), 256, 0, stream>>>(w0, wc0);
  conv_w_kernel<64><<<dim3(8, 16), 256, 0, stream>>>(w1, wc1);

  if (twopass) {
    edge_mfma<32, true><<<NBLK_EDGE, 256, 0, stream>>>(xh0, wc0, chunkcell,
                                                       srcS, posS, basS, msg, nullptr);
    pass2_kernel<32><<<NN / 4, 256, 0, stream>>>(msg, dstbase, degi, x0, root0, b0, x1, xh1);
    edge_mfma<64, true><<<NBLK_EDGE, 256, 0, stream>>>(xh1, wc1, chunkcell,
                                                       srcS, posS, basS, msg, nullptr);
    pass2_kernel<64><<<NN / 4, 256, 0, stream>>>(msg, dstbase, degi, x1, root1, b1, x2, xh1);
  } else {
    hipMemsetAsync(agg, 0, sizeof(float) * NN * 64, stream);
    edge_mfma<32, false><<<NBLK_EDGE, 256, 0, stream>>>(xh0, wc0, chunkcell,
                                                        srcS, posS, basS, nullptr, agg);
    finalize_kernel<32><<<(NN + 3) / 4, 256, 0, stream>>>(x0, agg, degi, root0, b0, x1, xh1);
    hipMemsetAsync(agg, 0, sizeof(float) * NN * 64, stream);
    edge_mfma<64, false><<<NBLK_EDGE, 256, 0, stream>>>(xh1, wc1, chunkcell,
                                                        srcS, posS, basS, nullptr, agg);
    finalize_kernel<64><<<(NN + 3) / 4, 256, 0, stream>>>(x1, agg, degi, root1, b1, x2, xh1);
  }

  out_kernel<<<(NN + 3) / 4, 256, 0, stream>>>(x0, x1, x2, fw, fb, out);
}

// Round 7
// 379.231 us; speedup vs baseline: 14.3787x; 1.2147x over previous
//
#include <hip/hip_runtime.h>
#include <hip/hip_bf16.h>
#include <hip/hip_fp16.h>

// SplineCNN forward, MI355X round 7.
// R6 -> R7: out_kernel (dense [50000x160]@[160x64]) was the top dispatch at
// 100us: serial 160-deep scalar fmaf chain per lane, MfmaUtil 0. Replaced
// with an MFMA GEMM (fp16 A from the existing xh side-copies, fw^T f16 in
// registers, bias in acc-init, no LDS). pass2<64> now writes xh2 (not xh1)
// so layer outputs stay live for the final GEMM.

typedef __attribute__((ext_vector_type(8))) _Float16 f16x8;
typedef __attribute__((ext_vector_type(4))) _Float16 f16x4;
typedef __attribute__((ext_vector_type(4))) float f32x4;

constexpr int NN = 50000;       // nodes
constexpr int EE = 800000;      // edges
constexpr int CHUNK = 256;      // edges per block in edge_mfma
constexpr int EB = EE / 256;    // 3125 prep/scatter blocks
static_assert(EE % 256 == 0, "prep grid assumes exact divisibility");
constexpr int ELIST_LEN = EE + 16 * CHUNK;
constexpr int NBLK_EDGE = ELIST_LEN / CHUNK;   // 3141

// ---------------------------------------------------------------- dtype probe
__global__ void detect_i64(const long long* __restrict__ eidx, int* __restrict__ flag) {
  long long v = eidx[threadIdx.x];
  bool ok = (v >= 0) && (v < (long long)NN);
  unsigned long long m = __ballot(ok);
  if (threadIdx.x == 0) flag[0] = (m == ~0ull) ? 1 : 0;
}

// ------------------------------------------------------------------- prep
__global__ __launch_bounds__(256) void prep_edges(
    const void* __restrict__ eidx, const float* __restrict__ attr,
    const int* __restrict__ flag,
    int* __restrict__ src, int* __restrict__ dst,
    int* __restrict__ cell, float4* __restrict__ basis,
    int* __restrict__ degi, int* __restrict__ bh) {
  __shared__ int wc[4][16];
  const int tid = threadIdx.x;
  const int e = blockIdx.x * 256 + tid;
  int s, d;
  if (flag[0]) {
    s = (int)((const long long*)eidx)[e];
    d = (int)((const long long*)eidx)[EE + e];
  } else {
    s = ((const int*)eidx)[e];
    d = ((const int*)eidx)[EE + e];
  }
  src[e] = s;
  dst[e] = d;
  atomicAdd(&degi[d], 1);
  float v0 = attr[2 * e] * 4.0f, v1 = attr[2 * e + 1] * 4.0f;
  float fl0 = floorf(v0), fl1 = floorf(v1);
  float fr0 = v0 - fl0, fr1 = v1 - fl1;
  int bx = min(max((int)fl0, 0), 3);
  int by = min(max((int)fl1, 0), 3);
  const int c = bx + 4 * by;
  cell[e] = c;
  float4 b;
  b.x = (1.0f - fr0) * (1.0f - fr1);
  b.y = fr0 * (1.0f - fr1);
  b.z = (1.0f - fr0) * fr1;
  b.w = fr0 * fr1;
  basis[e] = b;
  const int wave = tid >> 6, lane = tid & 63;
#pragma unroll
  for (int k = 0; k < 16; ++k) {
    unsigned long long mm = __ballot(c == k);
    if (lane == k) wc[wave][k] = __popcll(mm);
  }
  __syncthreads();
  if (tid < 16)
    bh[blockIdx.x * 16 + tid] = wc[0][tid] + wc[1][tid] + wc[2][tid] + wc[3][tid];
}

// One block, 16 waves: per-cell totals, padded offsets, per-block bases,
// and the chunk -> cell map for the edge kernel grid.
__global__ __launch_bounds__(1024) void scan_offsets(
    const int* __restrict__ bh, int* __restrict__ blkbase,
    int* __restrict__ chunkcell) {
  __shared__ int tot[16];
  __shared__ int ofs_s[16];
  const int wave = threadIdx.x >> 6, lane = threadIdx.x & 63;
  {
    int sum = 0;
    for (int b = lane; b < EB; b += 64) sum += bh[b * 16 + wave];
#pragma unroll
    for (int off = 32; off > 0; off >>= 1) sum += __shfl_down(sum, off);
    if (lane == 0) tot[wave] = sum;
  }
  __syncthreads();
  if (threadIdx.x == 0) {
    int t = 0;
    for (int c = 0; c < 16; ++c) {
      ofs_s[c] = t;
      t += ((tot[c] + CHUNK - 1) / CHUNK) * CHUNK;
    }
  }
  __syncthreads();
  {  // chunk -> cell map (wave w owns cell w); padding chunks get -1
    const int nch = (tot[wave] + CHUNK - 1) / CHUNK;
    const int cb = ofs_s[wave] / CHUNK;
    for (int i = lane; i < nch; i += 64) chunkcell[cb + i] = wave;
    if (wave == 15) {
      const int totch = cb + nch;
      for (int i = totch + lane; i < NBLK_EDGE; i += 64) chunkcell[i] = -1;
    }
  }
  int running = ofs_s[wave];
  for (int b0 = 0; b0 < EB; b0 += 64) {
    const int b = b0 + lane;
    const int v = (b < EB) ? bh[b * 16 + wave] : 0;
    int inc = v;
#pragma unroll
    for (int off = 1; off < 64; off <<= 1) {
      int n = __shfl_up(inc, off);
      if (lane >= off) inc += n;
    }
    if (b < EB) blkbase[b * 16 + wave] = running + (inc - v);
    running += __shfl(inc, 63);
  }
}

// Exclusive prefix over the 50k degree histogram (one block, 16 waves).
__global__ __launch_bounds__(1024) void scan_deg(
    const int* __restrict__ degi, int* __restrict__ dstbase) {
  __shared__ int wsum[16];
  __shared__ int stot;
  const int wave = threadIdx.x >> 6, lane = threadIdx.x & 63;
  int running = 0;
  for (int base = 0; base < NN; base += 1024) {
    const int i = base + (int)threadIdx.x;
    const int v = (i < NN) ? degi[i] : 0;
    int inc = v;
#pragma unroll
    for (int off = 1; off < 64; off <<= 1) {
      int n = __shfl_up(inc, off);
      if (lane >= off) inc += n;
    }
    if (lane == 63) wsum[wave] = inc;
    __syncthreads();
    if (threadIdx.x == 0) {
      int t = 0;
      for (int w2 = 0; w2 < 16; ++w2) { int tv = wsum[w2]; wsum[w2] = t; t += tv; }
      stot = t;
    }
    __syncthreads();
    if (i < NN) dstbase[i] = running + wsum[wave] + (inc - v);
    running += stot;
    __syncthreads();
  }
}

// Deterministic cell-sorted scatter of ALL per-edge metadata.
__global__ __launch_bounds__(256) void scatter_edges(
    const int* __restrict__ cell, const int* __restrict__ blkbase,
    const int* __restrict__ srcArr, const int* __restrict__ dst,
    const float4* __restrict__ basis, const int* __restrict__ dstbase,
    int* __restrict__ fill2,
    int* __restrict__ srcS, int* __restrict__ posS, float4* __restrict__ basS) {
  __shared__ int wc[4][16];
  __shared__ int bs[4][16];
  const int tid = threadIdx.x;
  const int e = blockIdx.x * 256 + tid;
  const int c = cell[e];
  const int wave = tid >> 6, lane = tid & 63;
  int rank = 0;
#pragma unroll
  for (int k = 0; k < 16; ++k) {
    unsigned long long mm = __ballot(c == k);
    if (k == c) rank = __popcll(mm & ((1ull << lane) - 1ull));
    if (lane == k) wc[wave][k] = __popcll(mm);
  }
  const int d = dst[e];
  const int mypos = dstbase[d] + atomicAdd(&fill2[d], 1);
  __syncthreads();
  if (tid < 16) {
    int running = blkbase[blockIdx.x * 16 + tid];
#pragma unroll
    for (int w = 0; w < 4; ++w) { bs[w][tid] = running; running += wc[w][tid]; }
  }
  __syncthreads();
  const int p = bs[wave][c] + rank;
  srcS[p] = srcArr[e];
  posS[p] = mypos;
  basS[p] = basis[e];
}

// ------------------------------------------------------ fp32 -> fp16 convert
template <int LEN8>   // LEN8 = total elems / 8
__global__ __launch_bounds__(256) void f2h_kernel(
    const float* __restrict__ in, _Float16* __restrict__ outh) {
  const int i = blockIdx.x * 256 + threadIdx.x;
  if (i >= LEN8) return;
  const float4 a = reinterpret_cast<const float4*>(in)[i * 2];
  const float4 b = reinterpret_cast<const float4*>(in)[i * 2 + 1];
  f16x8 v = {(_Float16)a.x, (_Float16)a.y, (_Float16)a.z, (_Float16)a.w,
             (_Float16)b.x, (_Float16)b.y, (_Float16)b.z, (_Float16)b.w};
  reinterpret_cast<f16x8*>(outh)[i] = v;
}

// ----------------------------------------------------- per-cell W images
template <int IN>
__global__ __launch_bounds__(256) void conv_w_kernel(
    const float* __restrict__ w, _Float16* __restrict__ wcell) {
  constexpr int K = 4 * IN;
  constexpr int RS = K * 2;
  constexpr int OPR = K / 8;
  const int c = blockIdx.y;
  const int o = blockIdx.x * 256 + threadIdx.x;   // < 64*OPR
  const int bx = c & 3, by = c >> 2;
  const int n = o / OPR;
  const int k0 = (o - n * OPR) * 8;
  const int ks = k0 >> 5;
  const int g2 = (k0 & 31) >> 3;
  const int s = (IN == 64) ? (ks & 3) : ks;
  const int i0 = ((IN == 64) ? (ks >> 2) * 32 : 0) + g2 * 8;
  const int kk = (bx + (s & 1)) + 5 * (by + (s >> 1));
  const float* wp = w + ((size_t)kk * IN + i0) * 64 + n;
  f16x8 v;
#pragma unroll
  for (int j = 0; j < 8; ++j) v[j] = (_Float16)wp[(size_t)j * 64];
  const int byte = n * RS + ((k0 * 2) ^ ((n & 15) << 4));
  *reinterpret_cast<f16x8*>(
      reinterpret_cast<char*>(wcell) + (size_t)c * (RS * 64) + byte) = v;
}

// fw [160][64] f32 -> fwT [64][160] f16 (B-operand image for out_mfma)
__global__ __launch_bounds__(256) void conv_fw_kernel(
    const float* __restrict__ fw, _Float16* __restrict__ fwT) {
  const int i = blockIdx.x * 256 + threadIdx.x;   // over 64*160
  if (i >= 64 * 160) return;
  const int n = i / 160, k = i - n * 160;
  fwT[i] = (_Float16)fw[k * 64 + n];
}

// ------------------------------------------------------------------- edge msg
template <int IN, bool TWOPASS>
__global__ __launch_bounds__(256) void edge_mfma(
    const _Float16* __restrict__ xh, const _Float16* __restrict__ wcell,
    const int* __restrict__ chunkcell,
    const int* __restrict__ srcS, const int* __restrict__ posS,
    const float4* __restrict__ basS,
    __half* __restrict__ msg, float* __restrict__ agg) {
  constexpr int K = 4 * IN;
  constexpr int KSTEPS = K / 32;
  constexpr int RS = K * 2;            // LDS row stride bytes
  constexpr int OPR = K / 8;           // 16B chunks per row
  constexpr int TILES = CHUNK / 64;    // 4
  constexpr int NCH = (IN == 64) ? 2 : 1;
  __shared__ f16x8 Wt[64 * OPR];
  const int tid = threadIdx.x;
  const int c = chunkcell[blockIdx.x];
  if (c < 0) return;                   // fully-padded chunk
  const int base = blockIdx.x * CHUNK;
  const int lane = tid & 63;
  const int wave = tid >> 6;
  const int g = lane >> 4, m = lane & 15;
  const int wbase = base + wave * (CHUNK / 4);
  // metadata prefetch: independent coalesced loads, issued before staging
  int sv_t[TILES], po_t[TILES];
  float4 bas_t[TILES];
#pragma unroll
  for (int t = 0; t < TILES; ++t) sv_t[t] = srcS[wbase + t * 16 + m];
#pragma unroll
  for (int t = 0; t < TILES; ++t) po_t[t] = posS[wbase + t * 16 + m];
#pragma unroll
  for (int t = 0; t < TILES; ++t) bas_t[t] = basS[wbase + t * 16 + m];
  // stage the prebuilt cell image: linear coalesced 16B copies
  {
    const f16x8* gw = reinterpret_cast<const f16x8*>(wcell) + (size_t)c * (64 * OPR);
    for (int o = tid; o < 64 * OPR; o += 256) Wt[o] = gw[o];
  }
  __syncthreads();
  // x gather (single dependent hop), all tiles in flight together
  f16x8 xc[TILES][NCH];
#pragma unroll
  for (int t = 0; t < TILES; ++t) {
    const int row = (sv_t[t] >= 0) ? sv_t[t] : 0;
    const f16x8* xr = reinterpret_cast<const f16x8*>(xh + (size_t)row * IN);
    xc[t][0] = xr[g];
    if constexpr (IN == 64) xc[t][1] = xr[4 + g];
  }
#pragma unroll
  for (int t = 0; t < TILES; ++t) {
    const _Float16 bhv[4] = {(_Float16)bas_t[t].x, (_Float16)bas_t[t].y,
                             (_Float16)bas_t[t].z, (_Float16)bas_t[t].w};
    f32x4 acc[4];
#pragma unroll
    for (int nt = 0; nt < 4; ++nt) acc[nt] = (f32x4){0.f, 0.f, 0.f, 0.f};
#pragma unroll
    for (int ks = 0; ks < KSTEPS; ++ks) {
      const int s = (IN == 64) ? (ks & 3) : ks;
      const f16x8 xin = (IN == 64 && (ks >> 2)) ? xc[t][1] : xc[t][0];
      const f16x8 a = xin * bhv[s];    // packed f16 mul
#pragma unroll
      for (int nt = 0; nt < 4; ++nt) {
        const int n = nt * 16 + m;
        const int byte = n * RS + (((ks * 64) + g * 16) ^ ((n & 15) << 4));
        acc[nt] = __builtin_amdgcn_mfma_f32_16x16x32_f16(a, Wt[byte >> 4], acc[nt], 0, 0, 0);
      }
    }
    // epilogue: D row = edge (lane>>4)*4+r, D col = nt*16 + (lane&15).
    // TWOPASS msg rows PERMUTED: channel nt*16+m stored at m*4+nt (8B store).
#pragma unroll
    for (int r = 0; r < 4; ++r) {
      const int m2 = g * 4 + r;
      const int er = __shfl(sv_t[t], m2);
      const int pr = __shfl(po_t[t], m2);
      if (er >= 0) {
        if constexpr (TWOPASS) {
          f16x4 pv = {(_Float16)acc[0][r], (_Float16)acc[1][r],
                      (_Float16)acc[2][r], (_Float16)acc[3][r]};
          *reinterpret_cast<f16x4*>(msg + (size_t)pr * 64 + m * 4) = pv;
        } else {
          float* ap = agg + (size_t)pr * 64 + m;
#pragma unroll
          for (int nt = 0; nt < 4; ++nt) atomicAdd(ap + nt * 16, acc[nt][r]);
        }
      }
    }
  }
}

// --------------------------------------------------------------- pass2
template <int IN>
__global__ __launch_bounds__(256) void pass2_kernel(
    const __half* __restrict__ msg, const int* __restrict__ dstbase,
    const int* __restrict__ degi, const float* __restrict__ x_in,
    const float* __restrict__ root, const float* __restrict__ bias,
    float* __restrict__ x_out, _Float16* __restrict__ xh_out) {
  __shared__ float rl[IN * 64];
  __shared__ float xs[4][IN];
  for (int idx = threadIdx.x; idx < IN * 16; idx += 256)
    reinterpret_cast<float4*>(rl)[idx] = reinterpret_cast<const float4*>(root)[idx];
  const int wave = threadIdx.x >> 6, lane = threadIdx.x & 63;
  const int n = blockIdx.x * 4 + wave;   // grid sized so n < NN always
  if (lane < IN / 4)
    reinterpret_cast<float4*>(xs[wave])[lane] =
        reinterpret_cast<const float4*>(x_in + (size_t)n * IN)[lane];
  __syncthreads();
  const int b0 = dstbase[n], dg = degi[n];
  // channel `lane` lives at permuted position (lane&15)*4 + (lane>>4)
  const __half* mp = msg + (size_t)b0 * 64 + ((lane & 15) * 4 + (lane >> 4));
  float acc = 0.f;
  int j = 0;
  for (; j + 4 <= dg; j += 4) {
    const float a0 = __half2float(mp[(size_t)(j + 0) * 64]);
    const float a1 = __half2float(mp[(size_t)(j + 1) * 64]);
    const float a2 = __half2float(mp[(size_t)(j + 2) * 64]);
    const float a3 = __half2float(mp[(size_t)(j + 3) * 64]);
    acc += (a0 + a1) + (a2 + a3);
  }
  for (; j < dg; ++j) acc += __half2float(mp[(size_t)j * 64]);
  float r = acc / fmaxf((float)dg, 1.0f) + bias[lane];
#pragma unroll 8
  for (int i = 0; i < IN; ++i) r = fmaf(xs[wave][i], rl[i * 64 + lane], r);
  r = fmaxf(r, 0.0f);
  x_out[(size_t)n * 64 + lane] = r;
  xh_out[(size_t)n * 64 + lane] = (_Float16)r;
}

// --------------------------------------------------------------- finalize
// (atomic-fallback path only)
template <int IN>
__global__ __launch_bounds__(256) void finalize_kernel(
    const float* __restrict__ x_in, const float* __restrict__ agg,
    const int* __restrict__ degi, const float* __restrict__ root,
    const float* __restrict__ bias, float* __restrict__ x_out,
    _Float16* __restrict__ xh_out) {
  __shared__ float rl[IN * 64];
  for (int idx = threadIdx.x; idx < IN * 16; idx += 256)
    reinterpret_cast<float4*>(rl)[idx] = reinterpret_cast<const float4*>(root)[idx];
  __syncthreads();
  const int wave = threadIdx.x >> 6, lane = threadIdx.x & 63;
  const int n = blockIdx.x * 4 + wave;
  if (n >= NN) return;
  const float d = fmaxf((float)degi[n], 1.0f);
  float r = agg[(size_t)n * 64 + lane] / d + bias[lane];
  const float* xr = x_in + (size_t)n * IN;
#pragma unroll 8
  for (int i = 0; i < IN; ++i) r = fmaf(xr[i], rl[i * 64 + lane], r);
  r = fmaxf(r, 0.0f);
  x_out[(size_t)n * 64 + lane] = r;
  xh_out[(size_t)n * 64 + lane] = (_Float16)r;
}

// ------------------------------------------------------------------- output
// out = [xh0|xh1|xh2] @ fwT^T + fb via MFMA. K=160 (5 k-steps), M-tile 16,
// 4 waves x 16 nodes = 64 nodes/block. B-frags in registers, no LDS.
__global__ __launch_bounds__(256) void out_mfma(
    const _Float16* __restrict__ xh0, const _Float16* __restrict__ xh1,
    const _Float16* __restrict__ xh2, const _Float16* __restrict__ fwT,
    const float* __restrict__ fb, float* __restrict__ out) {
  const int lane = threadIdx.x & 63, wave = threadIdx.x >> 6;
  const int g = lane >> 4, m = lane & 15;
  const int base = blockIdx.x * 64 + wave * 16;   // NN % 16 == 0
  if (base >= NN) return;
  // B fragments: col n = nt*16+m, k = ks*32 + g*8 + j
  f16x8 bf[5][4];
#pragma unroll
  for (int ks = 0; ks < 5; ++ks)
#pragma unroll
    for (int nt = 0; nt < 4; ++nt)
      bf[ks][nt] = *reinterpret_cast<const f16x8*>(
          fwT + (size_t)(nt * 16 + m) * 160 + ks * 32 + g * 8);
  // A fragments: row = base+m, k-chunks from the three xh arrays
  const int row = base + m;
  f16x8 a[5];
  a[0] = *reinterpret_cast<const f16x8*>(xh0 + (size_t)row * 32 + g * 8);
  a[1] = *reinterpret_cast<const f16x8*>(xh1 + (size_t)row * 64 + g * 8);
  a[2] = *reinterpret_cast<const f16x8*>(xh1 + (size_t)row * 64 + 32 + g * 8);
  a[3] = *reinterpret_cast<const f16x8*>(xh2 + (size_t)row * 64 + g * 8);
  a[4] = *reinterpret_cast<const f16x8*>(xh2 + (size_t)row * 64 + 32 + g * 8);
  f32x4 acc[4];
#pragma unroll
  for (int nt = 0; nt < 4; ++nt) {
    const float fv = fb[nt * 16 + m];
    acc[nt] = (f32x4){fv, fv, fv, fv};
  }
#pragma unroll
  for (int ks = 0; ks < 5; ++ks)
#pragma unroll
    for (int nt = 0; nt < 4; ++nt)
      acc[nt] = __builtin_amdgcn_mfma_f32_16x16x32_f16(a[ks], bf[ks][nt], acc[nt], 0, 0, 0);
  // D: row = base + g*4 + r, col = nt*16 + m
#pragma unroll
  for (int r = 0; r < 4; ++r) {
    float* op = out + (size_t)(base + g * 4 + r) * 64 + m;
#pragma unroll
    for (int nt = 0; nt < 4; ++nt) op[nt * 16] = acc[nt][r];
  }
}

extern "C" void kernel_launch(void* const* d_in, const int* in_sizes, int n_in,
                              void* d_out, int out_size, void* d_ws, size_t ws_size,
                              hipStream_t stream) {
  const float* x0 = (const float*)d_in[0];
  const void* eidx = d_in[1];
  const float* attr = (const float*)d_in[2];
  const float* w0 = (const float*)d_in[3];
  const float* root0 = (const float*)d_in[4];
  const float* b0 = (const float*)d_in[5];
  const float* w1 = (const float*)d_in[6];
  const float* root1 = (const float*)d_in[7];
  const float* b1 = (const float*)d_in[8];
  const float* fw = (const float*)d_in[9];
  const float* fb = (const float*)d_in[10];
  float* out = (float*)d_out;
  (void)in_sizes; (void)n_in; (void)out_size;

  char* wsb = (char*)d_ws;
  size_t off = 0;
  auto alloc = [&](size_t bytes) -> void* {
    void* p = wsb + off;
    off += (bytes + 255) & ~(size_t)255;
    return p;
  };
  int* flag = (int*)alloc(256);
  int* src = (int*)alloc(sizeof(int) * EE);
  int* dst = (int*)alloc(sizeof(int) * EE);
  int* cell = (int*)alloc(sizeof(int) * EE);
  float4* basis = (float4*)alloc(sizeof(float4) * EE);
  int* srcS = (int*)alloc(sizeof(int) * ELIST_LEN);
  int* posS = (int*)alloc(sizeof(int) * ELIST_LEN);
  float4* basS = (float4*)alloc(sizeof(float4) * ELIST_LEN);
  int* chunkcell = (int*)alloc(sizeof(int) * NBLK_EDGE);
  int* degi = (int*)alloc(sizeof(int) * NN);
  int* dstbase = (int*)alloc(sizeof(int) * NN);
  int* fill2 = (int*)alloc(sizeof(int) * NN);
  int* bh = (int*)alloc(sizeof(int) * EB * 16);
  int* blkbase = (int*)alloc(sizeof(int) * EB * 16);
  float* x1 = (float*)alloc(sizeof(float) * NN * 64);
  float* x2 = (float*)alloc(sizeof(float) * NN * 64);
  _Float16* xh0 = (_Float16*)alloc(sizeof(_Float16) * NN * 32);
  _Float16* xh1 = (_Float16*)alloc(sizeof(_Float16) * NN * 64);
  _Float16* xh2 = (_Float16*)alloc(sizeof(_Float16) * NN * 64);
  _Float16* wc0 = (_Float16*)alloc(sizeof(_Float16) * 16 * 128 * 64);  // 256KB
  _Float16* wc1 = (_Float16*)alloc(sizeof(_Float16) * 16 * 256 * 64);  // 512KB
  _Float16* fwT = (_Float16*)alloc(sizeof(_Float16) * 64 * 160);
  const size_t common = off;
  const bool twopass = ws_size >= common + sizeof(__half) * (size_t)EE * 64;
  __half* msg = nullptr;
  float* agg = nullptr;
  if (twopass) msg = (__half*)alloc(sizeof(__half) * (size_t)EE * 64);
  else         agg = (float*)alloc(sizeof(float) * (size_t)NN * 64);

  hipMemsetAsync(degi, 0, sizeof(int) * NN, stream);
  hipMemsetAsync(fill2, 0, sizeof(int) * NN, stream);
  hipMemsetAsync(srcS, 0xFF, sizeof(int) * ELIST_LEN, stream);  // -1 sentinels

  detect_i64<<<1, 64, 0, stream>>>((const long long*)eidx, flag);
  prep_edges<<<EB, 256, 0, stream>>>(eidx, attr, flag, src, dst, cell, basis, degi, bh);
  scan_offsets<<<1, 1024, 0, stream>>>(bh, blkbase, chunkcell);
  scan_deg<<<1, 1024, 0, stream>>>(degi, dstbase);
  scatter_edges<<<EB, 256, 0, stream>>>(cell, blkbase, src, dst, basis, dstbase,
                                        fill2, srcS, posS, basS);
  constexpr int L0_8 = NN * 32 / 8;
  f2h_kernel<L0_8><<<(L0_8 + 255) / 256, 256, 0, stream>>>(x0, xh0);
  conv_w_kernel<32><<<dim3(4, 16), 256, 0, stream>>>(w0, wc0);
  conv_w_kernel<64><<<dim3(8, 16), 256, 0, stream>>>(w1, wc1);
  conv_fw_kernel<<<(64 * 160 + 255) / 256, 256, 0, stream>>>(fw, fwT);

  if (twopass) {
    edge_mfma<32, true><<<NBLK_EDGE, 256, 0, stream>>>(xh0, wc0, chunkcell,
                                                       srcS, posS, basS, msg, nullptr);
    pass2_kernel<32><<<NN / 4, 256, 0, stream>>>(msg, dstbase, degi, x0, root0, b0, x1, xh1);
    edge_mfma<64, true><<<NBLK_EDGE, 256, 0, stream>>>(xh1, wc1, chunkcell,
                                                       srcS, posS, basS, msg, nullptr);
    pass2_kernel<64><<<NN / 4, 256, 0, stream>>>(msg, dstbase, degi, x1, root1, b1, x2, xh2);
  } else {
    hipMemsetAsync(agg, 0, sizeof(float) * NN * 64, stream);
    edge_mfma<32, false><<<NBLK_EDGE, 256, 0, stream>>>(xh0, wc0, chunkcell,
                                                        srcS, posS, basS, nullptr, agg);
    finalize_kernel<32><<<(NN + 3) / 4, 256, 0, stream>>>(x0, agg, degi, root0, b0, x1, xh1);
    hipMemsetAsync(agg, 0, sizeof(float) * NN * 64, stream);
    edge_mfma<64, false><<<NBLK_EDGE, 256, 0, stream>>>(xh1, wc1, chunkcell,
                                                        srcS, posS, basS, nullptr, agg);
    finalize_kernel<64><<<(NN + 3) / 4, 256, 0, stream>>>(x1, agg, degi, root1, b1, x2, xh2);
  }

  out_mfma<<<(NN + 63) / 64, 256, 0, stream>>>(xh0, xh1, xh2, fwT, fb, out);
}

// Round 8
// 291.512 us; speedup vs baseline: 18.7054x; 1.3009x over previous
//
#include <hip/hip_runtime.h>
#include <hip/hip_bf16.h>
#include <hip/hip_fp16.h>

// SplineCNN forward, MI355X round 8.
// R7 -> R8: scan_offsets was the top dispatch (66us): single block, 49 serial
// iterations of uncoalesced stride-64B loads + serial carry chain; scan_deg
// had the same shape. Replaced both with ONE 2-block kernel (blocks run
// concurrently): transposed histogram bhT[16][EB] for coalesced loads, all 49
// chunks preloaded into registers (static-indexed full unroll), serial part
// reduced to 49 register shfl-scans per wave.

typedef __attribute__((ext_vector_type(8))) _Float16 f16x8;
typedef __attribute__((ext_vector_type(4))) _Float16 f16x4;
typedef __attribute__((ext_vector_type(4))) float f32x4;

constexpr int NN = 50000;       // nodes
constexpr int EE = 800000;      // edges
constexpr int CHUNK = 256;      // edges per block in edge_mfma
constexpr int EB = EE / 256;    // 3125 prep/scatter blocks
static_assert(EE % 256 == 0, "prep grid assumes exact divisibility");
constexpr int ELIST_LEN = EE + 16 * CHUNK;
constexpr int NBLK_EDGE = ELIST_LEN / CHUNK;   // 3141

// ---------------------------------------------------------------- dtype probe
__global__ void detect_i64(const long long* __restrict__ eidx, int* __restrict__ flag) {
  long long v = eidx[threadIdx.x];
  bool ok = (v >= 0) && (v < (long long)NN);
  unsigned long long m = __ballot(ok);
  if (threadIdx.x == 0) flag[0] = (m == ~0ull) ? 1 : 0;
}

// ------------------------------------------------------------------- prep
__global__ __launch_bounds__(256) void prep_edges(
    const void* __restrict__ eidx, const float* __restrict__ attr,
    const int* __restrict__ flag,
    int* __restrict__ src, int* __restrict__ dst,
    int* __restrict__ cell, float4* __restrict__ basis,
    int* __restrict__ degi, int* __restrict__ bhT) {
  __shared__ int wc[4][16];
  const int tid = threadIdx.x;
  const int e = blockIdx.x * 256 + tid;
  int s, d;
  if (flag[0]) {
    s = (int)((const long long*)eidx)[e];
    d = (int)((const long long*)eidx)[EE + e];
  } else {
    s = ((const int*)eidx)[e];
    d = ((const int*)eidx)[EE + e];
  }
  src[e] = s;
  dst[e] = d;
  atomicAdd(&degi[d], 1);
  float v0 = attr[2 * e] * 4.0f, v1 = attr[2 * e + 1] * 4.0f;
  float fl0 = floorf(v0), fl1 = floorf(v1);
  float fr0 = v0 - fl0, fr1 = v1 - fl1;
  int bx = min(max((int)fl0, 0), 3);
  int by = min(max((int)fl1, 0), 3);
  const int c = bx + 4 * by;
  cell[e] = c;
  float4 b;
  b.x = (1.0f - fr0) * (1.0f - fr1);
  b.y = fr0 * (1.0f - fr1);
  b.z = (1.0f - fr0) * fr1;
  b.w = fr0 * fr1;
  basis[e] = b;
  const int wave = tid >> 6, lane = tid & 63;
#pragma unroll
  for (int k = 0; k < 16; ++k) {
    unsigned long long mm = __ballot(c == k);
    if (lane == k) wc[wave][k] = __popcll(mm);
  }
  __syncthreads();
  if (tid < 16)
    bhT[tid * EB + blockIdx.x] = wc[0][tid] + wc[1][tid] + wc[2][tid] + wc[3][tid];
}

// --------------------------------------------------------------- fused scans
// Block 0: per-cell padded offsets + per-block scatter bases (bhT->blkbaseT)
//          + chunk->cell map. Block 1: degree exclusive prefix (degi->dstbase).
// Both: coalesced preload of all chunks into registers, then shfl-scan chain.
__global__ __launch_bounds__(1024) void scan_fused(
    const int* __restrict__ bhT, int* __restrict__ blkbaseT,
    int* __restrict__ chunkcell,
    const int* __restrict__ degi, int* __restrict__ dstbase) {
  const int wave = threadIdx.x >> 6, lane = threadIdx.x & 63;
  if (blockIdx.x == 0) {
    constexpr int CH = (EB + 63) / 64;   // 49
    __shared__ int ofs_s[16];
    __shared__ int tot_s[16];
    int v[CH];
#pragma unroll
    for (int ch = 0; ch < CH; ++ch) {
      const int b = ch * 64 + lane;
      v[ch] = (b < EB) ? bhT[wave * EB + b] : 0;
    }
    {  // wave totals from registers
      int sum = 0;
#pragma unroll
      for (int ch = 0; ch < CH; ++ch) sum += v[ch];
#pragma unroll
      for (int off = 32; off > 0; off >>= 1) sum += __shfl_down(sum, off);
      if (lane == 0) tot_s[wave] = sum;
    }
    __syncthreads();
    if (threadIdx.x == 0) {
      int t = 0;
      for (int c = 0; c < 16; ++c) {
        ofs_s[c] = t;
        t += ((tot_s[c] + CHUNK - 1) / CHUNK) * CHUNK;
      }
    }
    __syncthreads();
    {  // chunk -> cell map; padding chunks get -1
      const int nch = (tot_s[wave] + CHUNK - 1) / CHUNK;
      const int cb = ofs_s[wave] / CHUNK;
      for (int i = lane; i < nch; i += 64) chunkcell[cb + i] = wave;
      if (wave == 15) {
        const int totch = cb + nch;
        for (int i = totch + lane; i < NBLK_EDGE; i += 64) chunkcell[i] = -1;
      }
    }
    int running = ofs_s[wave];
#pragma unroll
    for (int ch = 0; ch < CH; ++ch) {
      int inc = v[ch];
#pragma unroll
      for (int off = 1; off < 64; off <<= 1) {
        int n = __shfl_up(inc, off);
        if (lane >= off) inc += n;
      }
      const int b = ch * 64 + lane;
      if (b < EB) blkbaseT[wave * EB + b] = running + inc - v[ch];
      running += __shfl(inc, 63);
    }
  } else {
    constexpr int SEG = NN / 16;          // 3125 contiguous nodes per wave
    constexpr int CH = (SEG + 63) / 64;   // 49
    __shared__ int wofs[16];
    const int nbase = wave * SEG;
    int v[CH];
#pragma unroll
    for (int ch = 0; ch < CH; ++ch) {
      const int i = ch * 64 + lane;
      v[ch] = (i < SEG) ? degi[nbase + i] : 0;
    }
    {
      int sum = 0;
#pragma unroll
      for (int ch = 0; ch < CH; ++ch) sum += v[ch];
#pragma unroll
      for (int off = 32; off > 0; off >>= 1) sum += __shfl_down(sum, off);
      if (lane == 0) wofs[wave] = sum;
    }
    __syncthreads();
    if (threadIdx.x == 0) {
      int t = 0;
      for (int w2 = 0; w2 < 16; ++w2) { int tv = wofs[w2]; wofs[w2] = t; t += tv; }
    }
    __syncthreads();
    int running = wofs[wave];
#pragma unroll
    for (int ch = 0; ch < CH; ++ch) {
      int inc = v[ch];
#pragma unroll
      for (int off = 1; off < 64; off <<= 1) {
        int n = __shfl_up(inc, off);
        if (lane >= off) inc += n;
      }
      const int i = ch * 64 + lane;
      if (i < SEG) dstbase[nbase + i] = running + inc - v[ch];
      running += __shfl(inc, 63);
    }
  }
}

// Deterministic cell-sorted scatter of ALL per-edge metadata.
__global__ __launch_bounds__(256) void scatter_edges(
    const int* __restrict__ cell, const int* __restrict__ blkbaseT,
    const int* __restrict__ srcArr, const int* __restrict__ dst,
    const float4* __restrict__ basis, const int* __restrict__ dstbase,
    int* __restrict__ fill2,
    int* __restrict__ srcS, int* __restrict__ posS, float4* __restrict__ basS) {
  __shared__ int wc[4][16];
  __shared__ int bs[4][16];
  const int tid = threadIdx.x;
  const int e = blockIdx.x * 256 + tid;
  const int c = cell[e];
  const int wave = tid >> 6, lane = tid & 63;
  int rank = 0;
#pragma unroll
  for (int k = 0; k < 16; ++k) {
    unsigned long long mm = __ballot(c == k);
    if (k == c) rank = __popcll(mm & ((1ull << lane) - 1ull));
    if (lane == k) wc[wave][k] = __popcll(mm);
  }
  const int d = dst[e];
  const int mypos = dstbase[d] + atomicAdd(&fill2[d], 1);
  __syncthreads();
  if (tid < 16) {
    int running = blkbaseT[tid * EB + blockIdx.x];
#pragma unroll
    for (int w = 0; w < 4; ++w) { bs[w][tid] = running; running += wc[w][tid]; }
  }
  __syncthreads();
  const int p = bs[wave][c] + rank;
  srcS[p] = srcArr[e];
  posS[p] = mypos;
  basS[p] = basis[e];
}

// ------------------------------------------------------ fp32 -> fp16 convert
template <int LEN8>   // LEN8 = total elems / 8
__global__ __launch_bounds__(256) void f2h_kernel(
    const float* __restrict__ in, _Float16* __restrict__ outh) {
  const int i = blockIdx.x * 256 + threadIdx.x;
  if (i >= LEN8) return;
  const float4 a = reinterpret_cast<const float4*>(in)[i * 2];
  const float4 b = reinterpret_cast<const float4*>(in)[i * 2 + 1];
  f16x8 v = {(_Float16)a.x, (_Float16)a.y, (_Float16)a.z, (_Float16)a.w,
             (_Float16)b.x, (_Float16)b.y, (_Float16)b.z, (_Float16)b.w};
  reinterpret_cast<f16x8*>(outh)[i] = v;
}

// ----------------------------------------------------- per-cell W images
template <int IN>
__global__ __launch_bounds__(256) void conv_w_kernel(
    const float* __restrict__ w, _Float16* __restrict__ wcell) {
  constexpr int K = 4 * IN;
  constexpr int RS = K * 2;
  constexpr int OPR = K / 8;
  const int c = blockIdx.y;
  const int o = blockIdx.x * 256 + threadIdx.x;   // < 64*OPR
  const int bx = c & 3, by = c >> 2;
  const int n = o / OPR;
  const int k0 = (o - n * OPR) * 8;
  const int ks = k0 >> 5;
  const int g2 = (k0 & 31) >> 3;
  const int s = (IN == 64) ? (ks & 3) : ks;
  const int i0 = ((IN == 64) ? (ks >> 2) * 32 : 0) + g2 * 8;
  const int kk = (bx + (s & 1)) + 5 * (by + (s >> 1));
  const float* wp = w + ((size_t)kk * IN + i0) * 64 + n;
  f16x8 v;
#pragma unroll
  for (int j = 0; j < 8; ++j) v[j] = (_Float16)wp[(size_t)j * 64];
  const int byte = n * RS + ((k0 * 2) ^ ((n & 15) << 4));
  *reinterpret_cast<f16x8*>(
      reinterpret_cast<char*>(wcell) + (size_t)c * (RS * 64) + byte) = v;
}

// fw [160][64] f32 -> fwT [64][160] f16 (B-operand image for out_mfma)
__global__ __launch_bounds__(256) void conv_fw_kernel(
    const float* __restrict__ fw, _Float16* __restrict__ fwT) {
  const int i = blockIdx.x * 256 + threadIdx.x;   // over 64*160
  if (i >= 64 * 160) return;
  const int n = i / 160, k = i - n * 160;
  fwT[i] = (_Float16)fw[k * 64 + n];
}

// ------------------------------------------------------------------- edge msg
template <int IN, bool TWOPASS>
__global__ __launch_bounds__(256) void edge_mfma(
    const _Float16* __restrict__ xh, const _Float16* __restrict__ wcell,
    const int* __restrict__ chunkcell,
    const int* __restrict__ srcS, const int* __restrict__ posS,
    const float4* __restrict__ basS,
    __half* __restrict__ msg, float* __restrict__ agg) {
  constexpr int K = 4 * IN;
  constexpr int KSTEPS = K / 32;
  constexpr int RS = K * 2;            // LDS row stride bytes
  constexpr int OPR = K / 8;           // 16B chunks per row
  constexpr int TILES = CHUNK / 64;    // 4
  constexpr int NCH = (IN == 64) ? 2 : 1;
  __shared__ f16x8 Wt[64 * OPR];
  const int tid = threadIdx.x;
  const int c = chunkcell[blockIdx.x];
  if (c < 0) return;                   // fully-padded chunk
  const int base = blockIdx.x * CHUNK;
  const int lane = tid & 63;
  const int wave = tid >> 6;
  const int g = lane >> 4, m = lane & 15;
  const int wbase = base + wave * (CHUNK / 4);
  // metadata prefetch: independent coalesced loads, issued before staging
  int sv_t[TILES], po_t[TILES];
  float4 bas_t[TILES];
#pragma unroll
  for (int t = 0; t < TILES; ++t) sv_t[t] = srcS[wbase + t * 16 + m];
#pragma unroll
  for (int t = 0; t < TILES; ++t) po_t[t] = posS[wbase + t * 16 + m];
#pragma unroll
  for (int t = 0; t < TILES; ++t) bas_t[t] = basS[wbase + t * 16 + m];
  // stage the prebuilt cell image: linear coalesced 16B copies
  {
    const f16x8* gw = reinterpret_cast<const f16x8*>(wcell) + (size_t)c * (64 * OPR);
    for (int o = tid; o < 64 * OPR; o += 256) Wt[o] = gw[o];
  }
  __syncthreads();
  // x gather (single dependent hop), all tiles in flight together
  f16x8 xc[TILES][NCH];
#pragma unroll
  for (int t = 0; t < TILES; ++t) {
    const int row = (sv_t[t] >= 0) ? sv_t[t] : 0;
    const f16x8* xr = reinterpret_cast<const f16x8*>(xh + (size_t)row * IN);
    xc[t][0] = xr[g];
    if constexpr (IN == 64) xc[t][1] = xr[4 + g];
  }
#pragma unroll
  for (int t = 0; t < TILES; ++t) {
    const _Float16 bhv[4] = {(_Float16)bas_t[t].x, (_Float16)bas_t[t].y,
                             (_Float16)bas_t[t].z, (_Float16)bas_t[t].w};
    f32x4 acc[4];
#pragma unroll
    for (int nt = 0; nt < 4; ++nt) acc[nt] = (f32x4){0.f, 0.f, 0.f, 0.f};
#pragma unroll
    for (int ks = 0; ks < KSTEPS; ++ks) {
      const int s = (IN == 64) ? (ks & 3) : ks;
      const f16x8 xin = (IN == 64 && (ks >> 2)) ? xc[t][1] : xc[t][0];
      const f16x8 a = xin * bhv[s];    // packed f16 mul
#pragma unroll
      for (int nt = 0; nt < 4; ++nt) {
        const int n = nt * 16 + m;
        const int byte = n * RS + (((ks * 64) + g * 16) ^ ((n & 15) << 4));
        acc[nt] = __builtin_amdgcn_mfma_f32_16x16x32_f16(a, Wt[byte >> 4], acc[nt], 0, 0, 0);
      }
    }
    // epilogue: D row = edge (lane>>4)*4+r, D col = nt*16 + (lane&15).
    // TWOPASS msg rows PERMUTED: channel nt*16+m stored at m*4+nt (8B store).
#pragma unroll
    for (int r = 0; r < 4; ++r) {
      const int m2 = g * 4 + r;
      const int er = __shfl(sv_t[t], m2);
      const int pr = __shfl(po_t[t], m2);
      if (er >= 0) {
        if constexpr (TWOPASS) {
          f16x4 pv = {(_Float16)acc[0][r], (_Float16)acc[1][r],
                      (_Float16)acc[2][r], (_Float16)acc[3][r]};
          *reinterpret_cast<f16x4*>(msg + (size_t)pr * 64 + m * 4) = pv;
        } else {
          float* ap = agg + (size_t)pr * 64 + m;
#pragma unroll
          for (int nt = 0; nt < 4; ++nt) atomicAdd(ap + nt * 16, acc[nt][r]);
        }
      }
    }
  }
}

// --------------------------------------------------------------- pass2
template <int IN>
__global__ __launch_bounds__(256) void pass2_kernel(
    const __half* __restrict__ msg, const int* __restrict__ dstbase,
    const int* __restrict__ degi, const float* __restrict__ x_in,
    const float* __restrict__ root, const float* __restrict__ bias,
    float* __restrict__ x_out, _Float16* __restrict__ xh_out) {
  __shared__ float rl[IN * 64];
  __shared__ float xs[4][IN];
  for (int idx = threadIdx.x; idx < IN * 16; idx += 256)
    reinterpret_cast<float4*>(rl)[idx] = reinterpret_cast<const float4*>(root)[idx];
  const int wave = threadIdx.x >> 6, lane = threadIdx.x & 63;
  const int n = blockIdx.x * 4 + wave;   // grid sized so n < NN always
  if (lane < IN / 4)
    reinterpret_cast<float4*>(xs[wave])[lane] =
        reinterpret_cast<const float4*>(x_in + (size_t)n * IN)[lane];
  __syncthreads();
  const int b0 = dstbase[n], dg = degi[n];
  // channel `lane` lives at permuted position (lane&15)*4 + (lane>>4)
  const __half* mp = msg + (size_t)b0 * 64 + ((lane & 15) * 4 + (lane >> 4));
  float acc = 0.f;
  int j = 0;
  for (; j + 4 <= dg; j += 4) {
    const float a0 = __half2float(mp[(size_t)(j + 0) * 64]);
    const float a1 = __half2float(mp[(size_t)(j + 1) * 64]);
    const float a2 = __half2float(mp[(size_t)(j + 2) * 64]);
    const float a3 = __half2float(mp[(size_t)(j + 3) * 64]);
    acc += (a0 + a1) + (a2 + a3);
  }
  for (; j < dg; ++j) acc += __half2float(mp[(size_t)j * 64]);
  float r = acc / fmaxf((float)dg, 1.0f) + bias[lane];
#pragma unroll 8
  for (int i = 0; i < IN; ++i) r = fmaf(xs[wave][i], rl[i * 64 + lane], r);
  r = fmaxf(r, 0.0f);
  x_out[(size_t)n * 64 + lane] = r;
  xh_out[(size_t)n * 64 + lane] = (_Float16)r;
}

// --------------------------------------------------------------- finalize
// (atomic-fallback path only)
template <int IN>
__global__ __launch_bounds__(256) void finalize_kernel(
    const float* __restrict__ x_in, const float* __restrict__ agg,
    const int* __restrict__ degi, const float* __restrict__ root,
    const float* __restrict__ bias, float* __restrict__ x_out,
    _Float16* __restrict__ xh_out) {
  __shared__ float rl[IN * 64];
  for (int idx = threadIdx.x; idx < IN * 16; idx += 256)
    reinterpret_cast<float4*>(rl)[idx] = reinterpret_cast<const float4*>(root)[idx];
  __syncthreads();
  const int wave = threadIdx.x >> 6, lane = threadIdx.x & 63;
  const int n = blockIdx.x * 4 + wave;
  if (n >= NN) return;
  const float d = fmaxf((float)degi[n], 1.0f);
  float r = agg[(size_t)n * 64 + lane] / d + bias[lane];
  const float* xr = x_in + (size_t)n * IN;
#pragma unroll 8
  for (int i = 0; i < IN; ++i) r = fmaf(xr[i], rl[i * 64 + lane], r);
  r = fmaxf(r, 0.0f);
  x_out[(size_t)n * 64 + lane] = r;
  xh_out[(size_t)n * 64 + lane] = (_Float16)r;
}

// ------------------------------------------------------------------- output
// out = [xh0|xh1|xh2] @ fwT^T + fb via MFMA. K=160 (5 k-steps), M-tile 16,
// 4 waves x 16 nodes = 64 nodes/block. B-frags in registers, no LDS.
__global__ __launch_bounds__(256) void out_mfma(
    const _Float16* __restrict__ xh0, const _Float16* __restrict__ xh1,
    const _Float16* __restrict__ xh2, const _Float16* __restrict__ fwT,
    const float* __restrict__ fb, float* __restrict__ out) {
  const int lane = threadIdx.x & 63, wave = threadIdx.x >> 6;
  const int g = lane >> 4, m = lane & 15;
  const int base = blockIdx.x * 64 + wave * 16;   // NN % 16 == 0
  if (base >= NN) return;
  // B fragments: col n = nt*16+m, k = ks*32 + g*8 + j
  f16x8 bf[5][4];
#pragma unroll
  for (int ks = 0; ks < 5; ++ks)
#pragma unroll
    for (int nt = 0; nt < 4; ++nt)
      bf[ks][nt] = *reinterpret_cast<const f16x8*>(
          fwT + (size_t)(nt * 16 + m) * 160 + ks * 32 + g * 8);
  // A fragments: row = base+m, k-chunks from the three xh arrays
  const int row = base + m;
  f16x8 a[5];
  a[0] = *reinterpret_cast<const f16x8*>(xh0 + (size_t)row * 32 + g * 8);
  a[1] = *reinterpret_cast<const f16x8*>(xh1 + (size_t)row * 64 + g * 8);
  a[2] = *reinterpret_cast<const f16x8*>(xh1 + (size_t)row * 64 + 32 + g * 8);
  a[3] = *reinterpret_cast<const f16x8*>(xh2 + (size_t)row * 64 + g * 8);
  a[4] = *reinterpret_cast<const f16x8*>(xh2 + (size_t)row * 64 + 32 + g * 8);
  f32x4 acc[4];
#pragma unroll
  for (int nt = 0; nt < 4; ++nt) {
    const float fv = fb[nt * 16 + m];
    acc[nt] = (f32x4){fv, fv, fv, fv};
  }
#pragma unroll
  for (int ks = 0; ks < 5; ++ks)
#pragma unroll
    for (int nt = 0; nt < 4; ++nt)
      acc[nt] = __builtin_amdgcn_mfma_f32_16x16x32_f16(a[ks], bf[ks][nt], acc[nt], 0, 0, 0);
  // D: row = base + g*4 + r, col = nt*16 + m
#pragma unroll
  for (int r = 0; r < 4; ++r) {
    float* op = out + (size_t)(base + g * 4 + r) * 64 + m;
#pragma unroll
    for (int nt = 0; nt < 4; ++nt) op[nt * 16] = acc[nt][r];
  }
}

extern "C" void kernel_launch(void* const* d_in, const int* in_sizes, int n_in,
                              void* d_out, int out_size, void* d_ws, size_t ws_size,
                              hipStream_t stream) {
  const float* x0 = (const float*)d_in[0];
  const void* eidx = d_in[1];
  const float* attr = (const float*)d_in[2];
  const float* w0 = (const float*)d_in[3];
  const float* root0 = (const float*)d_in[4];
  const float* b0 = (const float*)d_in[5];
  const float* w1 = (const float*)d_in[6];
  const float* root1 = (const float*)d_in[7];
  const float* b1 = (const float*)d_in[8];
  const float* fw = (const float*)d_in[9];
  const float* fb = (const float*)d_in[10];
  float* out = (float*)d_out;
  (void)in_sizes; (void)n_in; (void)out_size;

  char* wsb = (char*)d_ws;
  size_t off = 0;
  auto alloc = [&](size_t bytes) -> void* {
    void* p = wsb + off;
    off += (bytes + 255) & ~(size_t)255;
    return p;
  };
  int* flag = (int*)alloc(256);
  int* src = (int*)alloc(sizeof(int) * EE);
  int* dst = (int*)alloc(sizeof(int) * EE);
  int* cell = (int*)alloc(sizeof(int) * EE);
  float4* basis = (float4*)alloc(sizeof(float4) * EE);
  int* srcS = (int*)alloc(sizeof(int) * ELIST_LEN);
  int* posS = (int*)alloc(sizeof(int) * ELIST_LEN);
  float4* basS = (float4*)alloc(sizeof(float4) * ELIST_LEN);
  int* chunkcell = (int*)alloc(sizeof(int) * NBLK_EDGE);
  int* degi = (int*)alloc(sizeof(int) * NN);
  int* dstbase = (int*)alloc(sizeof(int) * NN);
  int* fill2 = (int*)alloc(sizeof(int) * NN);
  int* bhT = (int*)alloc(sizeof(int) * EB * 16);
  int* blkbaseT = (int*)alloc(sizeof(int) * EB * 16);
  float* x1 = (float*)alloc(sizeof(float) * NN * 64);
  float* x2 = (float*)alloc(sizeof(float) * NN * 64);
  _Float16* xh0 = (_Float16*)alloc(sizeof(_Float16) * NN * 32);
  _Float16* xh1 = (_Float16*)alloc(sizeof(_Float16) * NN * 64);
  _Float16* xh2 = (_Float16*)alloc(sizeof(_Float16) * NN * 64);
  _Float16* wc0 = (_Float16*)alloc(sizeof(_Float16) * 16 * 128 * 64);  // 256KB
  _Float16* wc1 = (_Float16*)alloc(sizeof(_Float16) * 16 * 256 * 64);  // 512KB
  _Float16* fwT = (_Float16*)alloc(sizeof(_Float16) * 64 * 160);
  const size_t common = off;
  const bool twopass = ws_size >= common + sizeof(__half) * (size_t)EE * 64;
  __half* msg = nullptr;
  float* agg = nullptr;
  if (twopass) msg = (__half*)alloc(sizeof(__half) * (size_t)EE * 64);
  else         agg = (float*)alloc(sizeof(float) * (size_t)NN * 64);

  hipMemsetAsync(degi, 0, sizeof(int) * NN, stream);
  hipMemsetAsync(fill2, 0, sizeof(int) * NN, stream);
  hipMemsetAsync(srcS, 0xFF, sizeof(int) * ELIST_LEN, stream);  // -1 sentinels

  detect_i64<<<1, 64, 0, stream>>>((const long long*)eidx, flag);
  prep_edges<<<EB, 256, 0, stream>>>(eidx, attr, flag, src, dst, cell, basis, degi, bhT);
  scan_fused<<<2, 1024, 0, stream>>>(bhT, blkbaseT, chunkcell, degi, dstbase);
  scatter_edges<<<EB, 256, 0, stream>>>(cell, blkbaseT, src, dst, basis, dstbase,
                                        fill2, srcS, posS, basS);
  constexpr int L0_8 = NN * 32 / 8;
  f2h_kernel<L0_8><<<(L0_8 + 255) / 256, 256, 0, stream>>>(x0, xh0);
  conv_w_kernel<32><<<dim3(4, 16), 256, 0, stream>>>(w0, wc0);
  conv_w_kernel<64><<<dim3(8, 16), 256, 0, stream>>>(w1, wc1);
  conv_fw_kernel<<<(64 * 160 + 255) / 256, 256, 0, stream>>>(fw, fwT);

  if (twopass) {
    edge_mfma<32, true><<<NBLK_EDGE, 256, 0, stream>>>(xh0, wc0, chunkcell,
                                                       srcS, posS, basS, msg, nullptr);
    pass2_kernel<32><<<NN / 4, 256, 0, stream>>>(msg, dstbase, degi, x0, root0, b0, x1, xh1);
    edge_mfma<64, true><<<NBLK_EDGE, 256, 0, stream>>>(xh1, wc1, chunkcell,
                                                       srcS, posS, basS, msg, nullptr);
    pass2_kernel<64><<<NN / 4, 256, 0, stream>>>(msg, dstbase, degi, x1, root1, b1, x2, xh2);
  } else {
    hipMemsetAsync(agg, 0, sizeof(float) * NN * 64, stream);
    edge_mfma<32, false><<<NBLK_EDGE, 256, 0, stream>>>(xh0, wc0, chunkcell,
                                                        srcS, posS, basS, nullptr, agg);
    finalize_kernel<32><<<(NN + 3) / 4, 256, 0, stream>>>(x0, agg, degi, root0, b0, x1, xh1);
    hipMemsetAsync(agg, 0, sizeof(float) * NN * 64, stream);
    edge_mfma<64, false><<<NBLK_EDGE, 256, 0, stream>>>(xh1, wc1, chunkcell,
                                                        srcS, posS, basS, nullptr, agg);
    finalize_kernel<64><<<(NN + 3) / 4, 256, 0, stream>>>(x1, agg, degi, root1, b1, x2, xh2);
  }

  out_mfma<<<(NN + 63) / 64, 256, 0, stream>>>(xh0, xh1, xh2, fwT, fb, out);
}